// Round 5
// baseline (351.135 us; speedup 1.0000x reference)
//
#include <hip/hip_runtime.h>
#include <math.h>

#define EPSF 1e-7f
#define MAXNF (1.0f - 1e-5f)

__device__ __forceinline__ float wsum(float v) {
#pragma unroll
  for (int off = 32; off >= 1; off >>= 1) v += __shfl_xor(v, off, 64);
  return v;
}

// Sum over each 16-lane group (lane&15 varies, lane>>4 fixed).
__device__ __forceinline__ float hsum16(float v) {
#pragma unroll
  for (int off = 8; off >= 1; off >>= 1) v += __shfl_xor(v, off, 64);
  return v;
}

__device__ __forceinline__ float dot4(const float4 a, const float4 b) {
  return a.x * b.x + a.y * b.y + a.z * b.z + a.w * b.w;
}

// One mobius_add step on a 256-dim vector, 4 elems/lane across a 64-lane wave.
__device__ __forceinline__ float4 mobius_step(const float4 x, const float4 y) {
  float px = wsum(dot4(x, x));
  float py = wsum(dot4(y, y));
  float pxy = wsum(dot4(x, y));
  float cx = 1.f + 2.f * pxy + py;
  float cy = 1.f - px;
  float inv = 1.f / fmaxf(1.f + 2.f * pxy + px * py, EPSF);
  float4 r;
  r.x = (cx * x.x + cy * y.x) * inv;
  r.y = (cx * x.y + cy * y.y) * inv;
  r.z = (cx * x.z + cy * y.z) * inv;
  r.w = (cx * x.w + cy * y.w) * inv;
  return r;
}

#define FMA4(ACC, S, BV)                                                      \
  ACC.x = fmaf(S, BV.x, ACC.x);                                               \
  ACC.y = fmaf(S, BV.y, ACC.y);                                               \
  ACC.z = fmaf(S, BV.z, ACC.z);                                               \
  ACC.w = fmaf(S, BV.w, ACC.w)

// Kernel 1: block = (j,k) pair, 256 threads = 4 waves. Wave w owns output
// cols [64w, 64w+64); lane = (rg = lane>>4) row-group x (cg = lane&15)
// col-group; per-lane tile 4 rows x 4 cols. A (raw feat rows) via L1
// broadcast loads (4 distinct 16B per instr); B (W1) via coalesced loads
// (256 B unique per instr, per-wave W1 traffic = 128 KB col slice).
// No LDS in hot loop; 0.25 scale folded into epilogue.
__global__ __launch_bounds__(256) void
k1_h1(const float* __restrict__ features, const float* __restrict__ W1,
      const float* __restrict__ b1, const int* __restrict__ src_idx,
      const int* __restrict__ to_fetch, float* __restrict__ h1) {
  const int blk = blockIdx.x;  // j*16 + k
  const int j = blk >> 4;
  const int k = blk & 15;
  const int tid = threadIdx.x;
  const int w = tid >> 6;
  const int lane = tid & 63;
  const int rg = lane >> 4;
  const int cg = lane & 15;
  const int c0 = (w << 6) + (cg << 2);

  __shared__ float trow[16][256];  // 16 KB
  __shared__ float s_msp[4][16];
  __shared__ float s_fs2[16], s_srow[16];
  __shared__ int s_vnode[16];
  __shared__ int s_a;

  if (tid == 0) s_a = src_idx[(to_fetch[j] + (j << 10)) * 16 + k];
  __syncthreads();
  if (tid < 16) s_vnode[tid] = src_idx[s_a * 16 + tid];
  __syncthreads();

  const float* fr[4];
#pragma unroll
  for (int i = 0; i < 4; ++i)
    fr[i] = features + (size_t)s_vnode[(rg << 2) + i] * 512;
  const float* wp = W1 + c0;

  float4 acc[4];
#pragma unroll
  for (int i = 0; i < 4; ++i) acc[i] = make_float4(0.f, 0.f, 0.f, 0.f);

  float4 Aa[4], Ba[4], Ab[4], Bb[4];
  auto loadA = [&](float4(&A)[4], int kx) {
#pragma unroll
    for (int i = 0; i < 4; ++i)
      A[i] = *reinterpret_cast<const float4*>(fr[i] + kx);
  };
  auto loadB = [&](float4(&B)[4], int kx) {
#pragma unroll
    for (int t = 0; t < 4; ++t)
      B[t] = *reinterpret_cast<const float4*>(wp + (kx + t) * 256);
  };
  auto fmaset = [&](const float4(&A)[4], const float4(&B)[4]) {
#pragma unroll
    for (int i = 0; i < 4; ++i) {
      FMA4(acc[i], A[i].x, B[0]);
      FMA4(acc[i], A[i].y, B[1]);
      FMA4(acc[i], A[i].z, B[2]);
      FMA4(acc[i], A[i].w, B[3]);
    }
  };

  loadA(Aa, 0);
  loadB(Ba, 0);
  loadA(Ab, 4);
  loadB(Bb, 4);
#pragma unroll 1
  for (int kk = 0; kk < 512; kk += 8) {
    fmaset(Aa, Ba);
    loadA(Aa, (kk + 8) & 511);
    loadB(Ba, (kk + 8) & 511);
    fmaset(Ab, Bb);
    loadA(Ab, (kk + 12) & 511);
    loadB(Bb, (kk + 12) & 511);
  }

  // ms2 partials: per-lane 4 rows over this wave's 64 cols -> 16-lane reduce.
  {
    float m[4];
#pragma unroll
    for (int i = 0; i < 4; ++i) m[i] = hsum16(dot4(acc[i], acc[i]));
    if (cg == 0) {
#pragma unroll
      for (int i = 0; i < 4; ++i) s_msp[w][(rg << 2) + i] = m[i];
    }
  }
  // fs2: wave w computes raw feature-row norms for rows 4w..4w+3.
  {
#pragma unroll
    for (int i = 0; i < 4; ++i) {
      const float* rp =
          features + (size_t)s_vnode[(w << 2) + i] * 512 + (lane << 3);
      const float4 f0 = *reinterpret_cast<const float4*>(rp);
      const float4 f1 = *reinterpret_cast<const float4*>(rp + 4);
      float s = dot4(f0, f0) + dot4(f1, f1);
      s = wsum(s);
      if (lane == 0) s_fs2[(w << 2) + i] = s;
    }
  }
  __syncthreads();
  if (tid < 16) {
    float ms2 = s_msp[0][tid] + s_msp[1][tid] + s_msp[2][tid] + s_msp[3][tid];
    float xn = fminf(fmaxf(0.25f * sqrtf(s_fs2[tid]), EPSF), MAXNF);
    float mxn = fmaxf(0.25f * sqrtf(ms2), EPSF);
    s_srow[tid] = tanhf(mxn / xn * atanhf(xn)) * 0.25f / mxn;
  }
  __syncthreads();

  // Scale + write transformed rows.
#pragma unroll
  for (int i = 0; i < 4; ++i) {
    const int r = (rg << 2) + i;
    const float s = s_srow[r];
    float4 t;
    t.x = acc[i].x * s; t.y = acc[i].y * s;
    t.z = acc[i].z * s; t.w = acc[i].w * s;
    *reinterpret_cast<float4*>(&trow[r][c0]) = t;
  }
  __syncthreads();

  // Chained mobius_add over the 16 rows, wave 0 only.
  if (tid < 64) {
    const int l4 = tid << 2;
    float4 x = *reinterpret_cast<const float4*>(&trow[0][l4]);
#pragma unroll 1
    for (int kk = 1; kk < 16; ++kk) {
      const float4 y = *reinterpret_cast<const float4*>(&trow[kk][l4]);
      x = mobius_step(x, y);
    }
    x.x *= 0.25f; x.y *= 0.25f; x.z *= 0.25f; x.w *= 0.25f;
    {
      const float4 b = *reinterpret_cast<const float4*>(b1 + l4);
      x = mobius_step(x, b);
    }
    // expmap0(relu(logmap0(x)))
    float pn = wsum(dot4(x, x));
    float yn = fminf(fmaxf(sqrtf(pn), EPSF), MAXNF);
    float s = atanhf(yn) / yn;
    float4 v;
    v.x = fmaxf(s * x.x, 0.f);
    v.y = fmaxf(s * x.y, 0.f);
    v.z = fmaxf(s * x.z, 0.f);
    v.w = fmaxf(s * x.w, 0.f);
    float pv = wsum(dot4(v, v));
    float vn = fmaxf(sqrtf(pv), EPSF);
    float s2 = tanhf(vn) / vn;
    float4 h;
    h.x = s2 * v.x;
    h.y = s2 * v.y;
    h.z = s2 * v.z;
    h.w = s2 * v.w;
    *reinterpret_cast<float4*>(h1 + (size_t)blk * 256 + l4) = h;
  }
}

// Kernel 2: one wave per output row j. Layer-2 aggregate+matvec+nonlinearity,
// then layer-3 classifier.
__global__ __launch_bounds__(64) void
k2_out(const float* __restrict__ h1, const float* __restrict__ W2,
       const float* __restrict__ b2, const float* __restrict__ Wl,
       const float* __restrict__ bl, float* __restrict__ out) {
  const int j = blockIdx.x;
  const int l = threadIdx.x;
  const int l4 = l << 2;
  __shared__ float xs[256];

  const float* base = h1 + (size_t)j * 16 * 256;
  float4 x = *reinterpret_cast<const float4*>(base + l4);
  x.x *= 0.25f; x.y *= 0.25f; x.z *= 0.25f; x.w *= 0.25f;
#pragma unroll 1
  for (int kk = 1; kk < 16; ++kk) {
    float4 y = *reinterpret_cast<const float4*>(base + kk * 256 + l4);
    y.x *= 0.25f; y.y *= 0.25f; y.z *= 0.25f; y.w *= 0.25f;
    x = mobius_step(x, y);
  }

  // mobius_matvec(x, W2): mx[n] = sum_d x[d] * W2[d][n]
  *reinterpret_cast<float4*>(&xs[l4]) = x;
  __syncthreads();
  float4 mx = make_float4(0.f, 0.f, 0.f, 0.f);
  for (int d = 0; d < 256; ++d) {
    const float xd = xs[d];
    const float4 w = *reinterpret_cast<const float4*>(W2 + d * 256 + l4);
    mx.x = fmaf(xd, w.x, mx.x);
    mx.y = fmaf(xd, w.y, mx.y);
    mx.z = fmaf(xd, w.z, mx.z);
    mx.w = fmaf(xd, w.w, mx.w);
  }
  {
    float px = wsum(dot4(x, x));
    float pm = wsum(dot4(mx, mx));
    float xn = fminf(fmaxf(sqrtf(px), EPSF), MAXNF);
    float mxn = fmaxf(sqrtf(pm), EPSF);
    float s = tanhf(mxn / xn * atanhf(xn)) / mxn;
    s *= 0.25f;  // rst * norm
    x.x = s * mx.x; x.y = s * mx.y; x.z = s * mx.z; x.w = s * mx.w;
  }
  {
    const float4 b = *reinterpret_cast<const float4*>(b2 + l4);
    x = mobius_step(x, b);
  }
  float pn = wsum(dot4(x, x));
  float yn = fminf(fmaxf(sqrtf(pn), EPSF), MAXNF);
  float s = atanhf(yn) / yn;
  float4 v;
  v.x = fmaxf(s * x.x, 0.f);
  v.y = fmaxf(s * x.y, 0.f);
  v.z = fmaxf(s * x.z, 0.f);
  v.w = fmaxf(s * x.w, 0.f);
  float pv = wsum(dot4(v, v));
  float vn = fmaxf(sqrtf(pv), EPSF);
  float s2 = tanhf(vn) / vn;
  float4 h;
  h.x = s2 * v.x; h.y = s2 * v.y; h.z = s2 * v.z; h.w = s2 * v.w;

  // Layer 3: mx2[o] = sum_d h[d] * Wl[o][d], o = lane.
  __syncthreads();
  *reinterpret_cast<float4*>(&xs[l4]) = h;
  __syncthreads();
  float m = 0.f;
  for (int d = 0; d < 256; d += 4) {
    const float4 w = *reinterpret_cast<const float4*>(Wl + (size_t)l * 256 + d);
    m = fmaf(w.x, xs[d + 0], m);
    m = fmaf(w.y, xs[d + 1], m);
    m = fmaf(w.z, xs[d + 2], m);
    m = fmaf(w.w, xs[d + 3], m);
  }
  float ph = wsum(dot4(h, h));
  float pmm = wsum(m * m);
  float hn = fminf(fmaxf(sqrtf(ph), EPSF), MAXNF);
  float mn = fmaxf(sqrtf(pmm), EPSF);
  float sc = tanhf(mn / hn * atanhf(hn)) / mn;
  float mo = sc * m;
  float bo = bl[l];
  float pxx = wsum(mo * mo);
  float pbb = wsum(bo * bo);
  float pxb = wsum(mo * bo);
  float cx = 1.f + 2.f * pxb + pbb;
  float cy = 1.f - pxx;
  float inv = 1.f / fmaxf(1.f + 2.f * pxb + pxx * pbb, EPSF);
  out[j * 64 + l] = (cx * mo + cy * bo) * inv;
}

extern "C" void kernel_launch(void* const* d_in, const int* in_sizes, int n_in,
                              void* d_out, int out_size, void* d_ws,
                              size_t ws_size, hipStream_t stream) {
  const float* features = (const float*)d_in[0];
  const float* W1 = (const float*)d_in[1];
  const float* b1 = (const float*)d_in[2];
  const float* W2 = (const float*)d_in[3];
  const float* b2 = (const float*)d_in[4];
  const float* Wl = (const float*)d_in[5];
  const float* bl = (const float*)d_in[6];
  const int* src_idx = (const int*)d_in[7];
  const int* to_fetch = (const int*)d_in[8];
  float* out = (float*)d_out;
  float* h1 = (float*)d_ws;  // 1024 * 256 floats = 1 MB scratch

  k1_h1<<<1024, 256, 0, stream>>>(features, W1, b1, src_idx, to_fetch, h1);
  k2_out<<<64, 64, 0, stream>>>(h1, W2, b2, Wl, bl, out);
}

// Round 6
// 68.613 us; speedup vs baseline: 5.1176x; 5.1176x over previous
//
#include <hip/hip_runtime.h>
#include <math.h>

#define EPSF 1e-7f
#define MAXNF (1.0f - 1e-5f)

typedef __attribute__((ext_vector_type(8))) short short8;
typedef __attribute__((ext_vector_type(4))) float f32x4;

union Pun8 { unsigned short u[8]; short8 s; };

static __device__ __forceinline__ unsigned short f2bf_rn(float f) {
  union { float f; unsigned u; } v;
  v.f = f;
  unsigned r = v.u + 0x7fff + ((v.u >> 16) & 1);  // RNE; inputs are finite
  return (unsigned short)(r >> 16);
}
static __device__ __forceinline__ float bf2f(unsigned short h) {
  union { unsigned u; float f; } v;
  v.u = ((unsigned)h) << 16;
  return v.f;
}

__device__ __forceinline__ float wsum(float v) {
#pragma unroll
  for (int off = 32; off >= 1; off >>= 1) v += __shfl_xor(v, off, 64);
  return v;
}
__device__ __forceinline__ float hsum16(float v) {
#pragma unroll
  for (int off = 8; off >= 1; off >>= 1) v += __shfl_xor(v, off, 64);
  return v;
}
__device__ __forceinline__ float dot4(const float4 a, const float4 b) {
  return a.x * b.x + a.y * b.y + a.z * b.z + a.w * b.w;
}
__device__ __forceinline__ float4 mobius_step(const float4 x, const float4 y) {
  float px = wsum(dot4(x, x));
  float py = wsum(dot4(y, y));
  float pxy = wsum(dot4(x, y));
  float cx = 1.f + 2.f * pxy + py;
  float cy = 1.f - px;
  float inv = 1.f / fmaxf(1.f + 2.f * pxy + px * py, EPSF);
  float4 r;
  r.x = (cx * x.x + cy * y.x) * inv;
  r.y = (cx * x.y + cy * y.y) * inv;
  r.z = (cx * x.z + cy * y.z) * inv;
  r.w = (cx * x.w + cy * y.w) * inv;
  return r;
}

// k0: pack W1 (512x256 f32) into bf16 hi/lo planes laid out in MFMA
// B-fragment order: element (s,t,lane,j) = W1[s*32 + (lane>>4)*8 + j][t*16 +
// (lane&15)] stored at short index ((s*16+t)*64+lane)*8 + j. One thread per
// (s,t,lane) handles 8 elems. 16384 threads total.
__global__ __launch_bounds__(256) void
k0_pack(const float* __restrict__ W1, unsigned short* __restrict__ hi,
        unsigned short* __restrict__ lo) {
  const int id = blockIdx.x * 256 + threadIdx.x;  // 0..16383
  const int s = id >> 10;
  const int t = (id >> 6) & 15;
  const int l = id & 63;
  const int n = t * 16 + (l & 15);
  const int k0 = s * 32 + ((l >> 4) << 3);
  Pun8 ph, pl;
#pragma unroll
  for (int jj = 0; jj < 8; ++jj) {
    float wv = W1[(k0 + jj) * 256 + n];
    unsigned short hb = f2bf_rn(wv);
    ph.u[jj] = hb;
    pl.u[jj] = f2bf_rn(wv - bf2f(hb));
  }
  *reinterpret_cast<short8*>(hi + id * 8) = ph.s;
  *reinterpret_cast<short8*>(lo + id * 8) = pl.s;
}

// k1: block = (j,k) pair, 256 threads = 4 waves. MFMA 16x16x32 bf16, bf16x3.
// Wave w computes n-tiles w*4..w*4+3 (cols w*64..w*64+63). A staged in LDS
// (hi/lo planes, XOR-swizzled); B read directly from packed ws (L2).
__global__ __launch_bounds__(256, 3) void
k1_h1(const float* __restrict__ features, const unsigned short* __restrict__ bhi,
      const unsigned short* __restrict__ blo, const float* __restrict__ b1,
      const int* __restrict__ src_idx, const int* __restrict__ to_fetch,
      float* __restrict__ h1) {
  const int blk = blockIdx.x;  // j*16 + k
  const int j = blk >> 4;
  const int k = blk & 15;
  const int tid = threadIdx.x;
  const int w = tid >> 6;
  const int lane = tid & 63;
  const int g = lane >> 4;
  const int r16 = lane & 15;

  __shared__ __align__(16) unsigned short aLDS[2][8192];  // 16 rows x 512 k
  __shared__ float s_msp[4][16];
  __shared__ float s_fs2[16], s_srow[16];
  __shared__ int s_vnode[16];
  __shared__ int s_a;

  if (tid == 0) s_a = src_idx[(to_fetch[j] + (j << 10)) * 16 + k];
  __syncthreads();
  if (tid < 16) s_vnode[tid] = src_idx[s_a * 16 + tid];
  __syncthreads();

  // Stage A: row r = w + 4i, chunk c = lane (8 floats). Swizzled bf16 hi/lo.
#pragma unroll
  for (int i = 0; i < 4; ++i) {
    const int r = w + 4 * i;
    const float* rp = features + (size_t)s_vnode[r] * 512 + lane * 8;
    const float4 f0 = *reinterpret_cast<const float4*>(rp);
    const float4 f1 = *reinterpret_cast<const float4*>(rp + 4);
    const float fv[8] = {f0.x, f0.y, f0.z, f0.w, f1.x, f1.y, f1.z, f1.w};
    Pun8 ph, pl;
    float ss = 0.f;
#pragma unroll
    for (int q = 0; q < 8; ++q) {
      ss = fmaf(fv[q], fv[q], ss);
      unsigned short hb = f2bf_rn(fv[q]);
      ph.u[q] = hb;
      pl.u[q] = f2bf_rn(fv[q] - bf2f(hb));
    }
    const int off = r * 512 + ((lane * 8) ^ ((r & 7) * 8));  // ushort units
    *reinterpret_cast<short8*>(&aLDS[0][off]) = ph.s;
    *reinterpret_cast<short8*>(&aLDS[1][off]) = pl.s;
    ss = wsum(ss);
    if (lane == 0) s_fs2[r] = ss;
  }
  __syncthreads();

  // Main MFMA loop over 16 k-steps (32 k each), software-pipelined by 2.
  const int g8 = g * 8;
  const int sw = (r16 & 7) * 8;
  const int arow = r16 * 512;
  const short8* Bh = reinterpret_cast<const short8*>(bhi);
  const short8* Bl = reinterpret_cast<const short8*>(blo);
  const int tbase = w * 4;

  f32x4 acc[4];
#pragma unroll
  for (int i = 0; i < 4; ++i) acc[i] = (f32x4){0.f, 0.f, 0.f, 0.f};

  short8 A0h, A0l, A1h, A1l;
  short8 B0h[4], B0l[4], B1h[4], B1l[4];

#define LOADA(AH, AL, S)                                                      \
  {                                                                           \
    const int o_ = arow + (((S)*32 + g8) ^ sw);                               \
    AH = *reinterpret_cast<const short8*>(&aLDS[0][o_]);                      \
    AL = *reinterpret_cast<const short8*>(&aLDS[1][o_]);                      \
  }
#define LOADB(BH, BL, S)                                                      \
  _Pragma("unroll") for (int i_ = 0; i_ < 4; ++i_) {                          \
    const int idx_ = ((S)*16 + tbase + i_) * 64 + lane;                       \
    BH[i_] = Bh[idx_];                                                        \
    BL[i_] = Bl[idx_];                                                        \
  }
#define MFMASET(AH, AL, BH, BL)                                               \
  _Pragma("unroll") for (int i_ = 0; i_ < 4; ++i_)                            \
      acc[i_] = __builtin_amdgcn_mfma_f32_16x16x32_bf16(AH, BH[i_], acc[i_],  \
                                                        0, 0, 0);             \
  _Pragma("unroll") for (int i_ = 0; i_ < 4; ++i_)                            \
      acc[i_] = __builtin_amdgcn_mfma_f32_16x16x32_bf16(AH, BL[i_], acc[i_],  \
                                                        0, 0, 0);             \
  _Pragma("unroll") for (int i_ = 0; i_ < 4; ++i_)                            \
      acc[i_] = __builtin_amdgcn_mfma_f32_16x16x32_bf16(AL, BH[i_], acc[i_],  \
                                                        0, 0, 0);

  LOADA(A0h, A0l, 0)
  LOADB(B0h, B0l, 0)
#pragma unroll 1
  for (int s = 0; s < 16; s += 2) {
    LOADA(A1h, A1l, s + 1)
    LOADB(B1h, B1l, s + 1)
    MFMASET(A0h, A0l, B0h, B0l)
    const int s2 = (s + 2) & 15;  // wraps on last iter (redundant, harmless)
    LOADA(A0h, A0l, s2)
    LOADB(B0h, B0l, s2)
    MFMASET(A1h, A1l, B1h, B1l)
  }

  // Row norms of mx: lane covers rows g*4+reg, cols tbase*16 + i*16 + r16.
  {
    float rs[4];
#pragma unroll
    for (int reg = 0; reg < 4; ++reg) {
      float v = 0.f;
#pragma unroll
      for (int i = 0; i < 4; ++i) v = fmaf(acc[i][reg], acc[i][reg], v);
      rs[reg] = hsum16(v);
    }
    if (r16 == 0) {
#pragma unroll
      for (int reg = 0; reg < 4; ++reg) s_msp[w][g * 4 + reg] = rs[reg];
    }
  }
  __syncthreads();
  if (tid < 16) {
    float ms2 = s_msp[0][tid] + s_msp[1][tid] + s_msp[2][tid] + s_msp[3][tid];
    float xn = fminf(fmaxf(0.25f * sqrtf(s_fs2[tid]), EPSF), MAXNF);
    float mxn = fmaxf(0.25f * sqrtf(ms2), EPSF);
    s_srow[tid] = tanhf(mxn / xn * atanhf(xn)) * 0.25f / mxn;
  }
  __syncthreads();

  // Scaled transformed rows into LDS (overlay on A hi plane, now dead).
  float(*trow)[256] = reinterpret_cast<float(*)[256]>(&aLDS[0][0]);
#pragma unroll
  for (int i = 0; i < 4; ++i) {
    const int n = (tbase + i) * 16 + r16;
#pragma unroll
    for (int reg = 0; reg < 4; ++reg) {
      const int row = g * 4 + reg;
      trow[row][n] = acc[i][reg] * s_srow[row];
    }
  }
  __syncthreads();

  // Chained mobius_add over the 16 rows, wave 0 only.
  if (tid < 64) {
    const int l4 = tid << 2;
    float4 x = *reinterpret_cast<const float4*>(&trow[0][l4]);
#pragma unroll 1
    for (int kk = 1; kk < 16; ++kk) {
      const float4 y = *reinterpret_cast<const float4*>(&trow[kk][l4]);
      x = mobius_step(x, y);
    }
    x.x *= 0.25f; x.y *= 0.25f; x.z *= 0.25f; x.w *= 0.25f;
    {
      const float4 b = *reinterpret_cast<const float4*>(b1 + l4);
      x = mobius_step(x, b);
    }
    float pn = wsum(dot4(x, x));
    float yn = fminf(fmaxf(sqrtf(pn), EPSF), MAXNF);
    float s = atanhf(yn) / yn;
    float4 v;
    v.x = fmaxf(s * x.x, 0.f);
    v.y = fmaxf(s * x.y, 0.f);
    v.z = fmaxf(s * x.z, 0.f);
    v.w = fmaxf(s * x.w, 0.f);
    float pv = wsum(dot4(v, v));
    float vn = fmaxf(sqrtf(pv), EPSF);
    float s2 = tanhf(vn) / vn;
    float4 h;
    h.x = s2 * v.x;
    h.y = s2 * v.y;
    h.z = s2 * v.z;
    h.w = s2 * v.w;
    *reinterpret_cast<float4*>(h1 + (size_t)blk * 256 + l4) = h;
  }
#undef LOADA
#undef LOADB
#undef MFMASET
}

// Kernel 2: one wave per output row j (unchanged fp32 path).
__global__ __launch_bounds__(64) void
k2_out(const float* __restrict__ h1, const float* __restrict__ W2,
       const float* __restrict__ b2, const float* __restrict__ Wl,
       const float* __restrict__ bl, float* __restrict__ out) {
  const int j = blockIdx.x;
  const int l = threadIdx.x;
  const int l4 = l << 2;
  __shared__ float xs[256];

  const float* base = h1 + (size_t)j * 16 * 256;
  float4 x = *reinterpret_cast<const float4*>(base + l4);
  x.x *= 0.25f; x.y *= 0.25f; x.z *= 0.25f; x.w *= 0.25f;
#pragma unroll 1
  for (int kk = 1; kk < 16; ++kk) {
    float4 y = *reinterpret_cast<const float4*>(base + kk * 256 + l4);
    y.x *= 0.25f; y.y *= 0.25f; y.z *= 0.25f; y.w *= 0.25f;
    x = mobius_step(x, y);
  }

  *reinterpret_cast<float4*>(&xs[l4]) = x;
  __syncthreads();
  float4 mx = make_float4(0.f, 0.f, 0.f, 0.f);
  for (int d = 0; d < 256; ++d) {
    const float xd = xs[d];
    const float4 wv = *reinterpret_cast<const float4*>(W2 + d * 256 + l4);
    mx.x = fmaf(xd, wv.x, mx.x);
    mx.y = fmaf(xd, wv.y, mx.y);
    mx.z = fmaf(xd, wv.z, mx.z);
    mx.w = fmaf(xd, wv.w, mx.w);
  }
  {
    float px = wsum(dot4(x, x));
    float pm = wsum(dot4(mx, mx));
    float xn = fminf(fmaxf(sqrtf(px), EPSF), MAXNF);
    float mxn = fmaxf(sqrtf(pm), EPSF);
    float s = tanhf(mxn / xn * atanhf(xn)) / mxn;
    s *= 0.25f;
    x.x = s * mx.x; x.y = s * mx.y; x.z = s * mx.z; x.w = s * mx.w;
  }
  {
    const float4 b = *reinterpret_cast<const float4*>(b2 + l4);
    x = mobius_step(x, b);
  }
  float pn = wsum(dot4(x, x));
  float yn = fminf(fmaxf(sqrtf(pn), EPSF), MAXNF);
  float s = atanhf(yn) / yn;
  float4 v;
  v.x = fmaxf(s * x.x, 0.f);
  v.y = fmaxf(s * x.y, 0.f);
  v.z = fmaxf(s * x.z, 0.f);
  v.w = fmaxf(s * x.w, 0.f);
  float pv = wsum(dot4(v, v));
  float vn = fmaxf(sqrtf(pv), EPSF);
  float s2 = tanhf(vn) / vn;
  float4 h;
  h.x = s2 * v.x; h.y = s2 * v.y; h.z = s2 * v.z; h.w = s2 * v.w;

  __syncthreads();
  *reinterpret_cast<float4*>(&xs[l4]) = h;
  __syncthreads();
  float m = 0.f;
  for (int d = 0; d < 256; d += 4) {
    const float4 wv = *reinterpret_cast<const float4*>(Wl + (size_t)l * 256 + d);
    m = fmaf(wv.x, xs[d + 0], m);
    m = fmaf(wv.y, xs[d + 1], m);
    m = fmaf(wv.z, xs[d + 2], m);
    m = fmaf(wv.w, xs[d + 3], m);
  }
  float ph = wsum(dot4(h, h));
  float pmm = wsum(m * m);
  float hn = fminf(fmaxf(sqrtf(ph), EPSF), MAXNF);
  float mn = fmaxf(sqrtf(pmm), EPSF);
  float sc = tanhf(mn / hn * atanhf(hn)) / mn;
  float mo = sc * m;
  float bo = bl[l];
  float pxx = wsum(mo * mo);
  float pbb = wsum(bo * bo);
  float pxb = wsum(mo * bo);
  float cx = 1.f + 2.f * pxb + pbb;
  float cy = 1.f - pxx;
  float inv = 1.f / fmaxf(1.f + 2.f * pxb + pxx * pbb, EPSF);
  out[j * 64 + l] = (cx * mo + cy * bo) * inv;
}

extern "C" void kernel_launch(void* const* d_in, const int* in_sizes, int n_in,
                              void* d_out, int out_size, void* d_ws,
                              size_t ws_size, hipStream_t stream) {
  const float* features = (const float*)d_in[0];
  const float* W1 = (const float*)d_in[1];
  const float* b1 = (const float*)d_in[2];
  const float* W2 = (const float*)d_in[3];
  const float* b2 = (const float*)d_in[4];
  const float* Wl = (const float*)d_in[5];
  const float* bl = (const float*)d_in[6];
  const int* src_idx = (const int*)d_in[7];
  const int* to_fetch = (const int*)d_in[8];
  float* out = (float*)d_out;

  float* h1 = (float*)d_ws;  // 1 MB
  unsigned short* whi = (unsigned short*)((char*)d_ws + (1u << 20));   // 256 KB
  unsigned short* wlo = (unsigned short*)((char*)d_ws + (1u << 20) + (1u << 18));

  k0_pack<<<64, 256, 0, stream>>>(W1, whi, wlo);
  k1_h1<<<1024, 256, 0, stream>>>(features, whi, wlo, b1, src_idx, to_fetch, h1);
  k2_out<<<64, 64, 0, stream>>>(h1, W2, b2, Wl, bl, out);
}

// Round 7
// 68.367 us; speedup vs baseline: 5.1361x; 1.0036x over previous
//
#include <hip/hip_runtime.h>
#include <math.h>

#define EPSF 1e-7f
#define MAXNF (1.0f - 1e-5f)

typedef __attribute__((ext_vector_type(8))) short short8;
typedef __attribute__((ext_vector_type(4))) float f32x4;

union Pun8 { unsigned short u[8]; short8 s; };

static __device__ __forceinline__ unsigned short f2bf_rn(float f) {
  union { float f; unsigned u; } v;
  v.f = f;
  unsigned r = v.u + 0x7fff + ((v.u >> 16) & 1);  // RNE; inputs are finite
  return (unsigned short)(r >> 16);
}
static __device__ __forceinline__ float bf2f(unsigned short h) {
  union { unsigned u; float f; } v;
  v.u = ((unsigned)h) << 16;
  return v.f;
}

__device__ __forceinline__ float wsum(float v) {
#pragma unroll
  for (int off = 32; off >= 1; off >>= 1) v += __shfl_xor(v, off, 64);
  return v;
}
__device__ __forceinline__ float hsum16(float v) {
#pragma unroll
  for (int off = 8; off >= 1; off >>= 1) v += __shfl_xor(v, off, 64);
  return v;
}
__device__ __forceinline__ float dot4(const float4 a, const float4 b) {
  return a.x * b.x + a.y * b.y + a.z * b.z + a.w * b.w;
}
__device__ __forceinline__ float4 mobius_step(const float4 x, const float4 y) {
  float px = wsum(dot4(x, x));
  float py = wsum(dot4(y, y));
  float pxy = wsum(dot4(x, y));
  float cx = 1.f + 2.f * pxy + py;
  float cy = 1.f - px;
  float inv = 1.f / fmaxf(1.f + 2.f * pxy + px * py, EPSF);
  float4 r;
  r.x = (cx * x.x + cy * y.x) * inv;
  r.y = (cx * x.y + cy * y.y) * inv;
  r.z = (cx * x.z + cy * y.z) * inv;
  r.w = (cx * x.w + cy * y.w) * inv;
  return r;
}

// k0: pack W1 (512x256 f32) into bf16 hi/lo planes in MFMA B-fragment order:
// element (s,t,lane,j) = W1[s*32 + (lane>>4)*8 + j][t*16 + (lane&15)] at
// short index ((s*16+t)*64+lane)*8 + j.
__global__ __launch_bounds__(256) void
k0_pack(const float* __restrict__ W1, unsigned short* __restrict__ hi,
        unsigned short* __restrict__ lo) {
  const int id = blockIdx.x * 256 + threadIdx.x;  // 0..16383
  const int s = id >> 10;
  const int t = (id >> 6) & 15;
  const int l = id & 63;
  const int n = t * 16 + (l & 15);
  const int k0 = s * 32 + ((l >> 4) << 3);
  Pun8 ph, pl;
#pragma unroll
  for (int jj = 0; jj < 8; ++jj) {
    float wv = W1[(k0 + jj) * 256 + n];
    unsigned short hb = f2bf_rn(wv);
    ph.u[jj] = hb;
    pl.u[jj] = f2bf_rn(wv - bf2f(hb));
  }
  *reinterpret_cast<short8*>(hi + id * 8) = ph.s;
  *reinterpret_cast<short8*>(lo + id * 8) = pl.s;
}

// k1: 256 blocks (1/CU), 256 threads = 4 waves. Each block computes 4
// (j,k) pairs = 64 gathered rows; wave w owns n-tiles 4w..4w+3 for ALL 4
// pairs (B frags reused 4x -> per-CU B traffic 512 KB; 48 MFMA per B set
// covers L2 latency). A staged in LDS bf16 hi/lo, XOR-swizzled, dbuf'd.
__global__ __launch_bounds__(256, 1) void
k1_h1(const float* __restrict__ features, const unsigned short* __restrict__ bhi,
      const unsigned short* __restrict__ blo, const float* __restrict__ b1,
      const int* __restrict__ src_idx, const int* __restrict__ to_fetch,
      float* __restrict__ h1) {
  const int b4 = blockIdx.x << 2;  // first pair index of this block
  const int tid = threadIdx.x;
  const int w = tid >> 6;
  const int lane = tid & 63;
  const int g = lane >> 4;
  const int r16 = lane & 15;

  __shared__ __align__(16) unsigned short aH[64 * 512];  // 64 KB
  __shared__ __align__(16) unsigned short aL[64 * 512];  // 64 KB
  __shared__ float s_msp[4][64];
  __shared__ float s_fs2[64], s_srow[64];
  __shared__ int s_anode[4];
  __shared__ int s_vn[64];

  if (tid < 4) {
    const int pair = b4 + tid;
    const int jj = pair >> 4, kk = pair & 15;
    s_anode[tid] = src_idx[(to_fetch[jj] + (jj << 10)) * 16 + kk];
  }
  __syncthreads();
  if (tid < 64) s_vn[tid] = src_idx[s_anode[tid >> 4] * 16 + (tid & 15)];
  __syncthreads();

  // Stage: wave w stages pair w's 16 rows (global rows w*16..w*16+15).
#pragma unroll 1
  for (int i = 0; i < 16; ++i) {
    const int r = w * 16 + i;
    const float* rp = features + (size_t)s_vn[r] * 512 + lane * 8;
    const float4 f0 = *reinterpret_cast<const float4*>(rp);
    const float4 f1 = *reinterpret_cast<const float4*>(rp + 4);
    const float fv[8] = {f0.x, f0.y, f0.z, f0.w, f1.x, f1.y, f1.z, f1.w};
    Pun8 ph, pl;
    float ss = 0.f;
#pragma unroll
    for (int q = 0; q < 8; ++q) {
      ss = fmaf(fv[q], fv[q], ss);
      unsigned short hb = f2bf_rn(fv[q]);
      ph.u[q] = hb;
      pl.u[q] = f2bf_rn(fv[q] - bf2f(hb));
    }
    const int off = r * 512 + ((lane * 8) ^ ((r & 7) * 8));
    *reinterpret_cast<short8*>(&aH[off]) = ph.s;
    *reinterpret_cast<short8*>(&aL[off]) = pl.s;
    ss = wsum(ss);
    if (lane == 0) s_fs2[r] = ss;
  }
  __syncthreads();

  const int g8 = g * 8;
  const int sw = (r16 & 7) * 8;
  const int tbase = w * 4;
  const short8* Bh = reinterpret_cast<const short8*>(bhi);
  const short8* Bl = reinterpret_cast<const short8*>(blo);

  f32x4 acc[4][4];  // [pair][ntile]
#pragma unroll
  for (int p = 0; p < 4; ++p)
#pragma unroll
    for (int i = 0; i < 4; ++i) acc[p][i] = (f32x4){0.f, 0.f, 0.f, 0.f};

  short8 A0[4][2], A1[4][2];  // [pair][hi/lo]
  short8 B0[4][2], B1[4][2];  // [ntile][hi/lo]

#define LOADA(AR, S)                                                          \
  {                                                                           \
    const int s_ = (S)&15;                                                    \
    _Pragma("unroll") for (int p_ = 0; p_ < 4; ++p_) {                        \
      const int o_ = ((p_ << 4) + r16) * 512 + (((s_ << 5) + g8) ^ sw);       \
      AR[p_][0] = *reinterpret_cast<const short8*>(&aH[o_]);                  \
      AR[p_][1] = *reinterpret_cast<const short8*>(&aL[o_]);                  \
    }                                                                         \
  }
#define LOADB(BR, S)                                                          \
  {                                                                           \
    const int s_ = (S)&15;                                                    \
    _Pragma("unroll") for (int i_ = 0; i_ < 4; ++i_) {                        \
      const int idx_ = ((s_ << 4) + tbase + i_) * 64 + lane;                  \
      BR[i_][0] = Bh[idx_];                                                   \
      BR[i_][1] = Bl[idx_];                                                   \
    }                                                                         \
  }
#define MFMAALL(AR, BR)                                                       \
  _Pragma("unroll") for (int p_ = 0; p_ < 4; ++p_)                            \
      _Pragma("unroll") for (int i_ = 0; i_ < 4; ++i_) acc[p_][i_] =          \
      __builtin_amdgcn_mfma_f32_16x16x32_bf16(AR[p_][0], BR[i_][0],           \
                                              acc[p_][i_], 0, 0, 0);          \
  _Pragma("unroll") for (int p_ = 0; p_ < 4; ++p_)                            \
      _Pragma("unroll") for (int i_ = 0; i_ < 4; ++i_) acc[p_][i_] =          \
      __builtin_amdgcn_mfma_f32_16x16x32_bf16(AR[p_][0], BR[i_][1],           \
                                              acc[p_][i_], 0, 0, 0);          \
  _Pragma("unroll") for (int p_ = 0; p_ < 4; ++p_)                            \
      _Pragma("unroll") for (int i_ = 0; i_ < 4; ++i_) acc[p_][i_] =          \
      __builtin_amdgcn_mfma_f32_16x16x32_bf16(AR[p_][1], BR[i_][0],           \
                                              acc[p_][i_], 0, 0, 0);

  LOADA(A0, 0)
  LOADB(B0, 0)
#pragma unroll 1
  for (int s = 0; s < 16; s += 2) {
    LOADA(A1, s + 1)
    LOADB(B1, s + 1)
    MFMAALL(A0, B0)
    LOADA(A0, s + 2)
    LOADB(B0, s + 2)
    MFMAALL(A1, B1)
  }

  // Row norms of mx: lane covers (pair p, rows g*4+reg), cols over its 4
  // n-tiles; hsum16 reduces over the 16 col-lanes; cross-wave sum in LDS.
#pragma unroll
  for (int p = 0; p < 4; ++p) {
    float rs[4];
#pragma unroll
    for (int reg = 0; reg < 4; ++reg) {
      float v = 0.f;
#pragma unroll
      for (int i = 0; i < 4; ++i) v = fmaf(acc[p][i][reg], acc[p][i][reg], v);
      rs[reg] = hsum16(v);
    }
    if (r16 == 0) {
#pragma unroll
      for (int reg = 0; reg < 4; ++reg)
        s_msp[w][(p << 4) + (g << 2) + reg] = rs[reg];
    }
  }
  __syncthreads();
  if (tid < 64) {
    const float ms2 =
        s_msp[0][tid] + s_msp[1][tid] + s_msp[2][tid] + s_msp[3][tid];
    const float xn = fminf(fmaxf(0.25f * sqrtf(s_fs2[tid]), EPSF), MAXNF);
    const float mxn = fmaxf(0.25f * sqrtf(ms2), EPSF);
    s_srow[tid] = tanhf(mxn / xn * atanhf(xn)) * 0.25f / mxn;
  }
  __syncthreads();

  // Scaled transformed rows overlay the (now dead) aH plane.
  float(*trow)[256] = reinterpret_cast<float(*)[256]>(&aH[0]);
#pragma unroll
  for (int p = 0; p < 4; ++p) {
#pragma unroll
    for (int i = 0; i < 4; ++i) {
      const int n = ((tbase + i) << 4) + r16;
#pragma unroll
      for (int reg = 0; reg < 4; ++reg) {
        const int row = (p << 4) + (g << 2) + reg;
        trow[row][n] = acc[p][i][reg] * s_srow[row];
      }
    }
  }
  __syncthreads();

  // Chained mobius_add: wave w processes pair w (rows w*16..w*16+15).
  {
    const int l4 = lane << 2;
    float4 x = *reinterpret_cast<const float4*>(&trow[w * 16][l4]);
#pragma unroll 1
    for (int kk = 1; kk < 16; ++kk) {
      const float4 y = *reinterpret_cast<const float4*>(&trow[w * 16 + kk][l4]);
      x = mobius_step(x, y);
    }
    x.x *= 0.25f; x.y *= 0.25f; x.z *= 0.25f; x.w *= 0.25f;
    {
      const float4 b = *reinterpret_cast<const float4*>(b1 + l4);
      x = mobius_step(x, b);
    }
    float pn = wsum(dot4(x, x));
    float yn = fminf(fmaxf(sqrtf(pn), EPSF), MAXNF);
    float s = atanhf(yn) / yn;
    float4 v;
    v.x = fmaxf(s * x.x, 0.f);
    v.y = fmaxf(s * x.y, 0.f);
    v.z = fmaxf(s * x.z, 0.f);
    v.w = fmaxf(s * x.w, 0.f);
    float pv = wsum(dot4(v, v));
    float vn = fmaxf(sqrtf(pv), EPSF);
    float s2 = tanhf(vn) / vn;
    float4 h;
    h.x = s2 * v.x;
    h.y = s2 * v.y;
    h.z = s2 * v.z;
    h.w = s2 * v.w;
    *reinterpret_cast<float4*>(h1 + (size_t)(b4 + w) * 256 + l4) = h;
  }
#undef LOADA
#undef LOADB
#undef MFMAALL
}

// Kernel 2: one wave per output row j (unchanged).
__global__ __launch_bounds__(64) void
k2_out(const float* __restrict__ h1, const float* __restrict__ W2,
       const float* __restrict__ b2, const float* __restrict__ Wl,
       const float* __restrict__ bl, float* __restrict__ out) {
  const int j = blockIdx.x;
  const int l = threadIdx.x;
  const int l4 = l << 2;
  __shared__ float xs[256];

  const float* base = h1 + (size_t)j * 16 * 256;
  float4 x = *reinterpret_cast<const float4*>(base + l4);
  x.x *= 0.25f; x.y *= 0.25f; x.z *= 0.25f; x.w *= 0.25f;
#pragma unroll 1
  for (int kk = 1; kk < 16; ++kk) {
    float4 y = *reinterpret_cast<const float4*>(base + kk * 256 + l4);
    y.x *= 0.25f; y.y *= 0.25f; y.z *= 0.25f; y.w *= 0.25f;
    x = mobius_step(x, y);
  }

  *reinterpret_cast<float4*>(&xs[l4]) = x;
  __syncthreads();
  float4 mx = make_float4(0.f, 0.f, 0.f, 0.f);
  for (int d = 0; d < 256; ++d) {
    const float xd = xs[d];
    const float4 wv = *reinterpret_cast<const float4*>(W2 + d * 256 + l4);
    mx.x = fmaf(xd, wv.x, mx.x);
    mx.y = fmaf(xd, wv.y, mx.y);
    mx.z = fmaf(xd, wv.z, mx.z);
    mx.w = fmaf(xd, wv.w, mx.w);
  }
  {
    float px = wsum(dot4(x, x));
    float pm = wsum(dot4(mx, mx));
    float xn = fminf(fmaxf(sqrtf(px), EPSF), MAXNF);
    float mxn = fmaxf(sqrtf(pm), EPSF);
    float s = tanhf(mxn / xn * atanhf(xn)) / mxn;
    s *= 0.25f;
    x.x = s * mx.x; x.y = s * mx.y; x.z = s * mx.z; x.w = s * mx.w;
  }
  {
    const float4 b = *reinterpret_cast<const float4*>(b2 + l4);
    x = mobius_step(x, b);
  }
  float pn = wsum(dot4(x, x));
  float yn = fminf(fmaxf(sqrtf(pn), EPSF), MAXNF);
  float s = atanhf(yn) / yn;
  float4 v;
  v.x = fmaxf(s * x.x, 0.f);
  v.y = fmaxf(s * x.y, 0.f);
  v.z = fmaxf(s * x.z, 0.f);
  v.w = fmaxf(s * x.w, 0.f);
  float pv = wsum(dot4(v, v));
  float vn = fmaxf(sqrtf(pv), EPSF);
  float s2 = tanhf(vn) / vn;
  float4 h;
  h.x = s2 * v.x; h.y = s2 * v.y; h.z = s2 * v.z; h.w = s2 * v.w;

  __syncthreads();
  *reinterpret_cast<float4*>(&xs[l4]) = h;
  __syncthreads();
  float m = 0.f;
  for (int d = 0; d < 256; d += 4) {
    const float4 wv = *reinterpret_cast<const float4*>(Wl + (size_t)l * 256 + d);
    m = fmaf(wv.x, xs[d + 0], m);
    m = fmaf(wv.y, xs[d + 1], m);
    m = fmaf(wv.z, xs[d + 2], m);
    m = fmaf(wv.w, xs[d + 3], m);
  }
  float ph = wsum(dot4(h, h));
  float pmm = wsum(m * m);
  float hn = fminf(fmaxf(sqrtf(ph), EPSF), MAXNF);
  float mn = fmaxf(sqrtf(pmm), EPSF);
  float sc = tanhf(mn / hn * atanhf(hn)) / mn;
  float mo = sc * m;
  float bo = bl[l];
  float pxx = wsum(mo * mo);
  float pbb = wsum(bo * bo);
  float pxb = wsum(mo * bo);
  float cx = 1.f + 2.f * pxb + pbb;
  float cy = 1.f - pxx;
  float inv = 1.f / fmaxf(1.f + 2.f * pxb + pxx * pbb, EPSF);
  out[j * 64 + l] = (cx * mo + cy * bo) * inv;
}

extern "C" void kernel_launch(void* const* d_in, const int* in_sizes, int n_in,
                              void* d_out, int out_size, void* d_ws,
                              size_t ws_size, hipStream_t stream) {
  const float* features = (const float*)d_in[0];
  const float* W1 = (const float*)d_in[1];
  const float* b1 = (const float*)d_in[2];
  const float* W2 = (const float*)d_in[3];
  const float* b2 = (const float*)d_in[4];
  const float* Wl = (const float*)d_in[5];
  const float* bl = (const float*)d_in[6];
  const int* src_idx = (const int*)d_in[7];
  const int* to_fetch = (const int*)d_in[8];
  float* out = (float*)d_out;

  float* h1 = (float*)d_ws;  // 1 MB
  unsigned short* whi = (unsigned short*)((char*)d_ws + (1u << 20));   // 256 KB
  unsigned short* wlo = (unsigned short*)((char*)d_ws + (1u << 20) + (1u << 18));

  k0_pack<<<64, 256, 0, stream>>>(W1, whi, wlo);
  k1_h1<<<256, 256, 0, stream>>>(features, whi, wlo, b1, src_idx, to_fetch, h1);
  k2_out<<<64, 64, 0, stream>>>(h1, W2, b2, Wl, bl, out);
}

// Round 8
// 61.176 us; speedup vs baseline: 5.7398x; 1.1175x over previous
//
#include <hip/hip_runtime.h>
#include <math.h>

#define EPSF 1e-7f
#define MAXNF (1.0f - 1e-5f)

typedef __attribute__((ext_vector_type(8))) short short8;
typedef __attribute__((ext_vector_type(4))) float f32x4;

union Pun8 { unsigned short u[8]; short8 s; };

static __device__ __forceinline__ unsigned short f2bf_rn(float f) {
  union { float f; unsigned u; } v;
  v.f = f;
  unsigned r = v.u + 0x7fff + ((v.u >> 16) & 1);  // RNE; inputs are finite
  return (unsigned short)(r >> 16);
}
static __device__ __forceinline__ float bf2f(unsigned short h) {
  union { unsigned u; float f; } v;
  v.u = ((unsigned)h) << 16;
  return v.f;
}

__device__ __forceinline__ float wsum(float v) {
#pragma unroll
  for (int off = 32; off >= 1; off >>= 1) v += __shfl_xor(v, off, 64);
  return v;
}
__device__ __forceinline__ float hsum16(float v) {
#pragma unroll
  for (int off = 8; off >= 1; off >>= 1) v += __shfl_xor(v, off, 64);
  return v;
}
__device__ __forceinline__ float dot4(const float4 a, const float4 b) {
  return a.x * b.x + a.y * b.y + a.z * b.z + a.w * b.w;
}
__device__ __forceinline__ float4 mobius_step(const float4 x, const float4 y) {
  float px = wsum(dot4(x, x));
  float py = wsum(dot4(y, y));
  float pxy = wsum(dot4(x, y));
  float cx = 1.f + 2.f * pxy + py;
  float cy = 1.f - px;
  float inv = 1.f / fmaxf(1.f + 2.f * pxy + px * py, EPSF);
  float4 r;
  r.x = (cx * x.x + cy * y.x) * inv;
  r.y = (cx * x.y + cy * y.y) * inv;
  r.z = (cx * x.z + cy * y.z) * inv;
  r.w = (cx * x.w + cy * y.w) * inv;
  return r;
}

// k0: pack W1 (512x256 f32) into bf16 hi/lo planes in MFMA B-fragment order:
// element (s,t,lane,j) = W1[s*32 + (lane>>4)*8 + j][t*16 + (lane&15)] at
// short index ((s*16+t)*64+lane)*8 + j.
__global__ __launch_bounds__(256) void
k0_pack(const float* __restrict__ W1, unsigned short* __restrict__ hi,
        unsigned short* __restrict__ lo) {
  const int id = blockIdx.x * 256 + threadIdx.x;  // 0..16383
  const int s = id >> 10;
  const int t = (id >> 6) & 15;
  const int l = id & 63;
  const int n = t * 16 + (l & 15);
  const int k0 = s * 32 + ((l >> 4) << 3);
  Pun8 ph, pl;
#pragma unroll
  for (int jj = 0; jj < 8; ++jj) {
    float wv = W1[(k0 + jj) * 256 + n];
    unsigned short hb = f2bf_rn(wv);
    ph.u[jj] = hb;
    pl.u[jj] = f2bf_rn(wv - bf2f(hb));
  }
  *reinterpret_cast<short8*>(hi + id * 8) = ph.s;
  *reinterpret_cast<short8*>(lo + id * 8) = pl.s;
}

// k1: 512 blocks (2/CU), 256 threads = 4 waves. Each block = 2 (j,k) pairs =
// 32 gathered rows in LDS (bf16 hi/lo, XOR-swizzled). Wave w owns n-tiles
// 4w..4w+3 for BOTH pairs. Staging is fully parallel: 8 rows/wave, loads
// batched 4 rows at a time (one latency window per batch). 8 waves/CU.
__global__ __launch_bounds__(256, 2) void
k1_h1(const float* __restrict__ features, const unsigned short* __restrict__ bhi,
      const unsigned short* __restrict__ blo, const float* __restrict__ b1,
      const int* __restrict__ src_idx, const int* __restrict__ to_fetch,
      float* __restrict__ h1) {
  const int b2 = blockIdx.x << 1;  // first pair index of this block
  const int tid = threadIdx.x;
  const int w = tid >> 6;
  const int lane = tid & 63;
  const int g = lane >> 4;
  const int r16 = lane & 15;

  __shared__ __align__(16) unsigned short aH[32 * 512];  // 32 KB
  __shared__ __align__(16) unsigned short aL[32 * 512];  // 32 KB
  __shared__ float s_msp[4][32];
  __shared__ float s_fs2[32], s_srow[32];
  __shared__ int s_anode[2];
  __shared__ int s_vn[32];

  if (tid < 2) {
    const int pair = b2 + tid;
    const int jj = pair >> 4, kk = pair & 15;
    s_anode[tid] = src_idx[(to_fetch[jj] + (jj << 10)) * 16 + kk];
  }
  __syncthreads();
  if (tid < 32) s_vn[tid] = src_idx[s_anode[tid >> 4] * 16 + (tid & 15)];
  __syncthreads();

  // Stage: wave w stages rows w*8..w*8+7, two batches of 4 rows with all
  // global loads issued before any consumption (overlapped HBM latency).
#pragma unroll
  for (int batch = 0; batch < 2; ++batch) {
    float4 f0[4], f1[4];
    const int rb = (w << 3) + (batch << 2);
#pragma unroll
    for (int i = 0; i < 4; ++i) {
      const float* rp = features + (size_t)s_vn[rb + i] * 512 + lane * 8;
      f0[i] = *reinterpret_cast<const float4*>(rp);
      f1[i] = *reinterpret_cast<const float4*>(rp + 4);
    }
#pragma unroll
    for (int i = 0; i < 4; ++i) {
      const int r = rb + i;
      const float fv[8] = {f0[i].x, f0[i].y, f0[i].z, f0[i].w,
                           f1[i].x, f1[i].y, f1[i].z, f1[i].w};
      Pun8 ph, pl;
      float ss = 0.f;
#pragma unroll
      for (int q = 0; q < 8; ++q) {
        ss = fmaf(fv[q], fv[q], ss);
        unsigned short hb = f2bf_rn(fv[q]);
        ph.u[q] = hb;
        pl.u[q] = f2bf_rn(fv[q] - bf2f(hb));
      }
      const int off = r * 512 + ((lane * 8) ^ ((r & 7) * 8));
      *reinterpret_cast<short8*>(&aH[off]) = ph.s;
      *reinterpret_cast<short8*>(&aL[off]) = pl.s;
      ss = wsum(ss);
      if (lane == 0) s_fs2[r] = ss;
    }
  }
  __syncthreads();

  const int g8 = g * 8;
  const int sw = (r16 & 7) * 8;
  const int tbase = w * 4;
  const short8* Bh = reinterpret_cast<const short8*>(bhi);
  const short8* Bl = reinterpret_cast<const short8*>(blo);

  f32x4 acc[2][4];  // [pair][ntile]
#pragma unroll
  for (int p = 0; p < 2; ++p)
#pragma unroll
    for (int i = 0; i < 4; ++i) acc[p][i] = (f32x4){0.f, 0.f, 0.f, 0.f};

  short8 A0[2][2], A1[2][2];  // [pair][hi/lo]
  short8 B0[4][2], B1[4][2];  // [ntile][hi/lo]

#define LOADA(AR, S)                                                          \
  {                                                                           \
    const int s_ = (S)&15;                                                    \
    _Pragma("unroll") for (int p_ = 0; p_ < 2; ++p_) {                        \
      const int o_ = ((p_ << 4) + r16) * 512 + (((s_ << 5) + g8) ^ sw);       \
      AR[p_][0] = *reinterpret_cast<const short8*>(&aH[o_]);                  \
      AR[p_][1] = *reinterpret_cast<const short8*>(&aL[o_]);                  \
    }                                                                         \
  }
#define LOADB(BR, S)                                                          \
  {                                                                           \
    const int s_ = (S)&15;                                                    \
    _Pragma("unroll") for (int i_ = 0; i_ < 4; ++i_) {                        \
      const int idx_ = ((s_ << 4) + tbase + i_) * 64 + lane;                  \
      BR[i_][0] = Bh[idx_];                                                   \
      BR[i_][1] = Bl[idx_];                                                   \
    }                                                                         \
  }
#define MFMAALL(AR, BR)                                                       \
  _Pragma("unroll") for (int p_ = 0; p_ < 2; ++p_)                            \
      _Pragma("unroll") for (int i_ = 0; i_ < 4; ++i_) acc[p_][i_] =          \
      __builtin_amdgcn_mfma_f32_16x16x32_bf16(AR[p_][0], BR[i_][0],           \
                                              acc[p_][i_], 0, 0, 0);          \
  _Pragma("unroll") for (int p_ = 0; p_ < 2; ++p_)                            \
      _Pragma("unroll") for (int i_ = 0; i_ < 4; ++i_) acc[p_][i_] =          \
      __builtin_amdgcn_mfma_f32_16x16x32_bf16(AR[p_][0], BR[i_][1],           \
                                              acc[p_][i_], 0, 0, 0);          \
  _Pragma("unroll") for (int p_ = 0; p_ < 2; ++p_)                            \
      _Pragma("unroll") for (int i_ = 0; i_ < 4; ++i_) acc[p_][i_] =          \
      __builtin_amdgcn_mfma_f32_16x16x32_bf16(AR[p_][1], BR[i_][0],           \
                                              acc[p_][i_], 0, 0, 0);

  LOADA(A0, 0)
  LOADB(B0, 0)
#pragma unroll 1
  for (int s = 0; s < 16; s += 2) {
    LOADA(A1, s + 1)
    LOADB(B1, s + 1)
    MFMAALL(A0, B0)
    LOADA(A0, s + 2)
    LOADB(B0, s + 2)
    MFMAALL(A1, B1)
  }

  // Row norms of mx: lane covers (pair p, rows g*4+reg); hsum16 reduces over
  // the 16 col-lanes of this wave's 64-col slice; cross-wave sum in LDS.
#pragma unroll
  for (int p = 0; p < 2; ++p) {
    float rs[4];
#pragma unroll
    for (int reg = 0; reg < 4; ++reg) {
      float v = 0.f;
#pragma unroll
      for (int i = 0; i < 4; ++i) v = fmaf(acc[p][i][reg], acc[p][i][reg], v);
      rs[reg] = hsum16(v);
    }
    if (r16 == 0) {
#pragma unroll
      for (int reg = 0; reg < 4; ++reg)
        s_msp[w][(p << 4) + (g << 2) + reg] = rs[reg];
    }
  }
  __syncthreads();
  if (tid < 32) {
    const float ms2 =
        s_msp[0][tid] + s_msp[1][tid] + s_msp[2][tid] + s_msp[3][tid];
    const float xn = fminf(fmaxf(0.25f * sqrtf(s_fs2[tid]), EPSF), MAXNF);
    const float mxn = fmaxf(0.25f * sqrtf(ms2), EPSF);
    s_srow[tid] = tanhf(mxn / xn * atanhf(xn)) * 0.25f / mxn;
  }
  __syncthreads();

  // Scaled transformed rows overlay the (now dead) aH plane.
  float(*trow)[256] = reinterpret_cast<float(*)[256]>(&aH[0]);
#pragma unroll
  for (int p = 0; p < 2; ++p) {
#pragma unroll
    for (int i = 0; i < 4; ++i) {
      const int n = ((tbase + i) << 4) + r16;
#pragma unroll
      for (int reg = 0; reg < 4; ++reg) {
        const int row = (p << 4) + (g << 2) + reg;
        trow[row][n] = acc[p][i][reg] * s_srow[row];
      }
    }
  }
  __syncthreads();

  // Chained mobius_add: waves 0 and 1 each process one pair.
  if (w < 2) {
    const int l4 = lane << 2;
    float4 x = *reinterpret_cast<const float4*>(&trow[w * 16][l4]);
#pragma unroll 1
    for (int kk = 1; kk < 16; ++kk) {
      const float4 y = *reinterpret_cast<const float4*>(&trow[w * 16 + kk][l4]);
      x = mobius_step(x, y);
    }
    x.x *= 0.25f; x.y *= 0.25f; x.z *= 0.25f; x.w *= 0.25f;
    {
      const float4 b = *reinterpret_cast<const float4*>(b1 + l4);
      x = mobius_step(x, b);
    }
    float pn = wsum(dot4(x, x));
    float yn = fminf(fmaxf(sqrtf(pn), EPSF), MAXNF);
    float s = atanhf(yn) / yn;
    float4 v;
    v.x = fmaxf(s * x.x, 0.f);
    v.y = fmaxf(s * x.y, 0.f);
    v.z = fmaxf(s * x.z, 0.f);
    v.w = fmaxf(s * x.w, 0.f);
    float pv = wsum(dot4(v, v));
    float vn = fmaxf(sqrtf(pv), EPSF);
    float s2 = tanhf(vn) / vn;
    float4 h;
    h.x = s2 * v.x;
    h.y = s2 * v.y;
    h.z = s2 * v.z;
    h.w = s2 * v.w;
    *reinterpret_cast<float4*>(h1 + (size_t)(b2 + w) * 256 + l4) = h;
  }
#undef LOADA
#undef LOADB
#undef MFMAALL
}

// Kernel 2: one wave per output row j (unchanged).
__global__ __launch_bounds__(64) void
k2_out(const float* __restrict__ h1, const float* __restrict__ W2,
       const float* __restrict__ b2, const float* __restrict__ Wl,
       const float* __restrict__ bl, float* __restrict__ out) {
  const int j = blockIdx.x;
  const int l = threadIdx.x;
  const int l4 = l << 2;
  __shared__ float xs[256];

  const float* base = h1 + (size_t)j * 16 * 256;
  float4 x = *reinterpret_cast<const float4*>(base + l4);
  x.x *= 0.25f; x.y *= 0.25f; x.z *= 0.25f; x.w *= 0.25f;
#pragma unroll 1
  for (int kk = 1; kk < 16; ++kk) {
    float4 y = *reinterpret_cast<const float4*>(base + kk * 256 + l4);
    y.x *= 0.25f; y.y *= 0.25f; y.z *= 0.25f; y.w *= 0.25f;
    x = mobius_step(x, y);
  }

  *reinterpret_cast<float4*>(&xs[l4]) = x;
  __syncthreads();
  float4 mx = make_float4(0.f, 0.f, 0.f, 0.f);
  for (int d = 0; d < 256; ++d) {
    const float xd = xs[d];
    const float4 wv = *reinterpret_cast<const float4*>(W2 + d * 256 + l4);
    mx.x = fmaf(xd, wv.x, mx.x);
    mx.y = fmaf(xd, wv.y, mx.y);
    mx.z = fmaf(xd, wv.z, mx.z);
    mx.w = fmaf(xd, wv.w, mx.w);
  }
  {
    float px = wsum(dot4(x, x));
    float pm = wsum(dot4(mx, mx));
    float xn = fminf(fmaxf(sqrtf(px), EPSF), MAXNF);
    float mxn = fmaxf(sqrtf(pm), EPSF);
    float s = tanhf(mxn / xn * atanhf(xn)) / mxn;
    s *= 0.25f;
    x.x = s * mx.x; x.y = s * mx.y; x.z = s * mx.z; x.w = s * mx.w;
  }
  {
    const float4 b = *reinterpret_cast<const float4*>(b2 + l4);
    x = mobius_step(x, b);
  }
  float pn = wsum(dot4(x, x));
  float yn = fminf(fmaxf(sqrtf(pn), EPSF), MAXNF);
  float s = atanhf(yn) / yn;
  float4 v;
  v.x = fmaxf(s * x.x, 0.f);
  v.y = fmaxf(s * x.y, 0.f);
  v.z = fmaxf(s * x.z, 0.f);
  v.w = fmaxf(s * x.w, 0.f);
  float pv = wsum(dot4(v, v));
  float vn = fmaxf(sqrtf(pv), EPSF);
  float s2 = tanhf(vn) / vn;
  float4 h;
  h.x = s2 * v.x; h.y = s2 * v.y; h.z = s2 * v.z; h.w = s2 * v.w;

  __syncthreads();
  *reinterpret_cast<float4*>(&xs[l4]) = h;
  __syncthreads();
  float m = 0.f;
  for (int d = 0; d < 256; d += 4) {
    const float4 wv = *reinterpret_cast<const float4*>(Wl + (size_t)l * 256 + d);
    m = fmaf(wv.x, xs[d + 0], m);
    m = fmaf(wv.y, xs[d + 1], m);
    m = fmaf(wv.z, xs[d + 2], m);
    m = fmaf(wv.w, xs[d + 3], m);
  }
  float ph = wsum(dot4(h, h));
  float pmm = wsum(m * m);
  float hn = fminf(fmaxf(sqrtf(ph), EPSF), MAXNF);
  float mn = fmaxf(sqrtf(pmm), EPSF);
  float sc = tanhf(mn / hn * atanhf(hn)) / mn;
  float mo = sc * m;
  float bo = bl[l];
  float pxx = wsum(mo * mo);
  float pbb = wsum(bo * bo);
  float pxb = wsum(mo * bo);
  float cx = 1.f + 2.f * pxb + pbb;
  float cy = 1.f - pxx;
  float inv = 1.f / fmaxf(1.f + 2.f * pxb + pxx * pbb, EPSF);
  out[j * 64 + l] = (cx * mo + cy * bo) * inv;
}

extern "C" void kernel_launch(void* const* d_in, const int* in_sizes, int n_in,
                              void* d_out, int out_size, void* d_ws,
                              size_t ws_size, hipStream_t stream) {
  const float* features = (const float*)d_in[0];
  const float* W1 = (const float*)d_in[1];
  const float* b1 = (const float*)d_in[2];
  const float* W2 = (const float*)d_in[3];
  const float* b2 = (const float*)d_in[4];
  const float* Wl = (const float*)d_in[5];
  const float* bl = (const float*)d_in[6];
  const int* src_idx = (const int*)d_in[7];
  const int* to_fetch = (const int*)d_in[8];
  float* out = (float*)d_out;

  float* h1 = (float*)d_ws;  // 1 MB
  unsigned short* whi = (unsigned short*)((char*)d_ws + (1u << 20));   // 256 KB
  unsigned short* wlo = (unsigned short*)((char*)d_ws + (1u << 20) + (1u << 18));

  k0_pack<<<64, 256, 0, stream>>>(W1, whi, wlo);
  k1_h1<<<512, 256, 0, stream>>>(features, whi, wlo, b1, src_idx, to_fetch, h1);
  k2_out<<<64, 64, 0, stream>>>(h1, W2, b2, Wl, bl, out);
}

// Round 9
// 53.732 us; speedup vs baseline: 6.5350x; 1.1385x over previous
//
#include <hip/hip_runtime.h>
#include <math.h>

#define EPSF 1e-7f
#define MAXNF (1.0f - 1e-5f)

typedef __attribute__((ext_vector_type(8))) short short8;
typedef __attribute__((ext_vector_type(4))) float f32x4;

union Pun8 { unsigned short u[8]; short8 s; };

static __device__ __forceinline__ unsigned short f2bf_rn(float f) {
  union { float f; unsigned u; } v;
  v.f = f;
  unsigned r = v.u + 0x7fff + ((v.u >> 16) & 1);  // RNE; inputs are finite
  return (unsigned short)(r >> 16);
}
static __device__ __forceinline__ float bf2f(unsigned short h) {
  union { unsigned u; float f; } v;
  v.u = ((unsigned)h) << 16;
  return v.f;
}

__device__ __forceinline__ float wsum(float v) {
#pragma unroll
  for (int off = 32; off >= 1; off >>= 1) v += __shfl_xor(v, off, 64);
  return v;
}
__device__ __forceinline__ float hsum16(float v) {
#pragma unroll
  for (int off = 8; off >= 1; off >>= 1) v += __shfl_xor(v, off, 64);
  return v;
}
__device__ __forceinline__ float dot4(const float4 a, const float4 b) {
  return a.x * b.x + a.y * b.y + a.z * b.z + a.w * b.w;
}
__device__ __forceinline__ float4 mobius_step(const float4 x, const float4 y) {
  float px = wsum(dot4(x, x));
  float py = wsum(dot4(y, y));
  float pxy = wsum(dot4(x, y));
  float cx = 1.f + 2.f * pxy + py;
  float cy = 1.f - px;
  float inv = 1.f / fmaxf(1.f + 2.f * pxy + px * py, EPSF);
  float4 r;
  r.x = (cx * x.x + cy * y.x) * inv;
  r.y = (cx * x.y + cy * y.y) * inv;
  r.z = (cx * x.z + cy * y.z) * inv;
  r.w = (cx * x.w + cy * y.w) * inv;
  return r;
}

// k0: pack W1 (512x256 f32) into bf16 hi/lo planes in MFMA B-fragment order
// (unchanged from round 8).
__global__ __launch_bounds__(256) void
k0_pack(const float* __restrict__ W1, unsigned short* __restrict__ hi,
        unsigned short* __restrict__ lo) {
  const int id = blockIdx.x * 256 + threadIdx.x;  // 0..16383
  const int s = id >> 10;
  const int t = (id >> 6) & 15;
  const int l = id & 63;
  const int n = t * 16 + (l & 15);
  const int k0 = s * 32 + ((l >> 4) << 3);
  Pun8 ph, pl;
#pragma unroll
  for (int jj = 0; jj < 8; ++jj) {
    float wv = W1[(k0 + jj) * 256 + n];
    unsigned short hb = f2bf_rn(wv);
    ph.u[jj] = hb;
    pl.u[jj] = f2bf_rn(wv - bf2f(hb));
  }
  *reinterpret_cast<short8*>(hi + id * 8) = ph.s;
  *reinterpret_cast<short8*>(lo + id * 8) = pl.s;
}

// k1: unchanged from round 8.
__global__ __launch_bounds__(256, 2) void
k1_h1(const float* __restrict__ features, const unsigned short* __restrict__ bhi,
      const unsigned short* __restrict__ blo, const float* __restrict__ b1,
      const int* __restrict__ src_idx, const int* __restrict__ to_fetch,
      float* __restrict__ h1) {
  const int b2 = blockIdx.x << 1;  // first pair index of this block
  const int tid = threadIdx.x;
  const int w = tid >> 6;
  const int lane = tid & 63;
  const int g = lane >> 4;
  const int r16 = lane & 15;

  __shared__ __align__(16) unsigned short aH[32 * 512];  // 32 KB
  __shared__ __align__(16) unsigned short aL[32 * 512];  // 32 KB
  __shared__ float s_msp[4][32];
  __shared__ float s_fs2[32], s_srow[32];
  __shared__ int s_anode[2];
  __shared__ int s_vn[32];

  if (tid < 2) {
    const int pair = b2 + tid;
    const int jj = pair >> 4, kk = pair & 15;
    s_anode[tid] = src_idx[(to_fetch[jj] + (jj << 10)) * 16 + kk];
  }
  __syncthreads();
  if (tid < 32) s_vn[tid] = src_idx[s_anode[tid >> 4] * 16 + (tid & 15)];
  __syncthreads();

#pragma unroll
  for (int batch = 0; batch < 2; ++batch) {
    float4 f0[4], f1[4];
    const int rb = (w << 3) + (batch << 2);
#pragma unroll
    for (int i = 0; i < 4; ++i) {
      const float* rp = features + (size_t)s_vn[rb + i] * 512 + lane * 8;
      f0[i] = *reinterpret_cast<const float4*>(rp);
      f1[i] = *reinterpret_cast<const float4*>(rp + 4);
    }
#pragma unroll
    for (int i = 0; i < 4; ++i) {
      const int r = rb + i;
      const float fv[8] = {f0[i].x, f0[i].y, f0[i].z, f0[i].w,
                           f1[i].x, f1[i].y, f1[i].z, f1[i].w};
      Pun8 ph, pl;
      float ss = 0.f;
#pragma unroll
      for (int q = 0; q < 8; ++q) {
        ss = fmaf(fv[q], fv[q], ss);
        unsigned short hb = f2bf_rn(fv[q]);
        ph.u[q] = hb;
        pl.u[q] = f2bf_rn(fv[q] - bf2f(hb));
      }
      const int off = r * 512 + ((lane * 8) ^ ((r & 7) * 8));
      *reinterpret_cast<short8*>(&aH[off]) = ph.s;
      *reinterpret_cast<short8*>(&aL[off]) = pl.s;
      ss = wsum(ss);
      if (lane == 0) s_fs2[r] = ss;
    }
  }
  __syncthreads();

  const int g8 = g * 8;
  const int sw = (r16 & 7) * 8;
  const int tbase = w * 4;
  const short8* Bh = reinterpret_cast<const short8*>(bhi);
  const short8* Bl = reinterpret_cast<const short8*>(blo);

  f32x4 acc[2][4];  // [pair][ntile]
#pragma unroll
  for (int p = 0; p < 2; ++p)
#pragma unroll
    for (int i = 0; i < 4; ++i) acc[p][i] = (f32x4){0.f, 0.f, 0.f, 0.f};

  short8 A0[2][2], A1[2][2];  // [pair][hi/lo]
  short8 B0[4][2], B1[4][2];  // [ntile][hi/lo]

#define LOADA(AR, S)                                                          \
  {                                                                           \
    const int s_ = (S)&15;                                                    \
    _Pragma("unroll") for (int p_ = 0; p_ < 2; ++p_) {                        \
      const int o_ = ((p_ << 4) + r16) * 512 + (((s_ << 5) + g8) ^ sw);       \
      AR[p_][0] = *reinterpret_cast<const short8*>(&aH[o_]);                  \
      AR[p_][1] = *reinterpret_cast<const short8*>(&aL[o_]);                  \
    }                                                                         \
  }
#define LOADB(BR, S)                                                          \
  {                                                                           \
    const int s_ = (S)&15;                                                    \
    _Pragma("unroll") for (int i_ = 0; i_ < 4; ++i_) {                        \
      const int idx_ = ((s_ << 4) + tbase + i_) * 64 + lane;                  \
      BR[i_][0] = Bh[idx_];                                                   \
      BR[i_][1] = Bl[idx_];                                                   \
    }                                                                         \
  }
#define MFMAALL(AR, BR)                                                       \
  _Pragma("unroll") for (int p_ = 0; p_ < 2; ++p_)                            \
      _Pragma("unroll") for (int i_ = 0; i_ < 4; ++i_) acc[p_][i_] =          \
      __builtin_amdgcn_mfma_f32_16x16x32_bf16(AR[p_][0], BR[i_][0],           \
                                              acc[p_][i_], 0, 0, 0);          \
  _Pragma("unroll") for (int p_ = 0; p_ < 2; ++p_)                            \
      _Pragma("unroll") for (int i_ = 0; i_ < 4; ++i_) acc[p_][i_] =          \
      __builtin_amdgcn_mfma_f32_16x16x32_bf16(AR[p_][0], BR[i_][1],           \
                                              acc[p_][i_], 0, 0, 0);          \
  _Pragma("unroll") for (int p_ = 0; p_ < 2; ++p_)                            \
      _Pragma("unroll") for (int i_ = 0; i_ < 4; ++i_) acc[p_][i_] =          \
      __builtin_amdgcn_mfma_f32_16x16x32_bf16(AR[p_][1], BR[i_][0],           \
                                              acc[p_][i_], 0, 0, 0);

  LOADA(A0, 0)
  LOADB(B0, 0)
#pragma unroll 1
  for (int s = 0; s < 16; s += 2) {
    LOADA(A1, s + 1)
    LOADB(B1, s + 1)
    MFMAALL(A0, B0)
    LOADA(A0, s + 2)
    LOADB(B0, s + 2)
    MFMAALL(A1, B1)
  }

#pragma unroll
  for (int p = 0; p < 2; ++p) {
    float rs[4];
#pragma unroll
    for (int reg = 0; reg < 4; ++reg) {
      float v = 0.f;
#pragma unroll
      for (int i = 0; i < 4; ++i) v = fmaf(acc[p][i][reg], acc[p][i][reg], v);
      rs[reg] = hsum16(v);
    }
    if (r16 == 0) {
#pragma unroll
      for (int reg = 0; reg < 4; ++reg)
        s_msp[w][(p << 4) + (g << 2) + reg] = rs[reg];
    }
  }
  __syncthreads();
  if (tid < 32) {
    const float ms2 =
        s_msp[0][tid] + s_msp[1][tid] + s_msp[2][tid] + s_msp[3][tid];
    const float xn = fminf(fmaxf(0.25f * sqrtf(s_fs2[tid]), EPSF), MAXNF);
    const float mxn = fmaxf(0.25f * sqrtf(ms2), EPSF);
    s_srow[tid] = tanhf(mxn / xn * atanhf(xn)) * 0.25f / mxn;
  }
  __syncthreads();

  float(*trow)[256] = reinterpret_cast<float(*)[256]>(&aH[0]);
#pragma unroll
  for (int p = 0; p < 2; ++p) {
#pragma unroll
    for (int i = 0; i < 4; ++i) {
      const int n = ((tbase + i) << 4) + r16;
#pragma unroll
      for (int reg = 0; reg < 4; ++reg) {
        const int row = (p << 4) + (g << 2) + reg;
        trow[row][n] = acc[p][i][reg] * s_srow[row];
      }
    }
  }
  __syncthreads();

  if (w < 2) {
    const int l4 = lane << 2;
    float4 x = *reinterpret_cast<const float4*>(&trow[w * 16][l4]);
#pragma unroll 1
    for (int kk = 1; kk < 16; ++kk) {
      const float4 y = *reinterpret_cast<const float4*>(&trow[w * 16 + kk][l4]);
      x = mobius_step(x, y);
    }
    x.x *= 0.25f; x.y *= 0.25f; x.z *= 0.25f; x.w *= 0.25f;
    {
      const float4 b = *reinterpret_cast<const float4*>(b1 + l4);
      x = mobius_step(x, b);
    }
    float pn = wsum(dot4(x, x));
    float yn = fminf(fmaxf(sqrtf(pn), EPSF), MAXNF);
    float s = atanhf(yn) / yn;
    float4 v;
    v.x = fmaxf(s * x.x, 0.f);
    v.y = fmaxf(s * x.y, 0.f);
    v.z = fmaxf(s * x.z, 0.f);
    v.w = fmaxf(s * x.w, 0.f);
    float pv = wsum(dot4(v, v));
    float vn = fmaxf(sqrtf(pv), EPSF);
    float s2 = tanhf(vn) / vn;
    float4 h;
    h.x = s2 * v.x;
    h.y = s2 * v.y;
    h.z = s2 * v.z;
    h.w = s2 * v.w;
    *reinterpret_cast<float4*>(h1 + (size_t)(b2 + w) * 256 + l4) = h;
  }
#undef LOADA
#undef LOADB
#undef MFMAALL
}

// Kernel 2 (REWRITTEN): 64 blocks x 256 threads (4 waves).
// (a) all waves prefetch the 16 h1 rows (x0.25) into LDS in parallel;
// (b) W2 matvec split across waves by 64-d quarter, partials reduced in LDS;
// (c) serial chain + nonlinearities on wave 0 from LDS.
__global__ __launch_bounds__(256) void
k2_out(const float* __restrict__ h1, const float* __restrict__ W2,
       const float* __restrict__ b2, const float* __restrict__ Wl,
       const float* __restrict__ bl, float* __restrict__ out) {
  const int j = blockIdx.x;
  const int tid = threadIdx.x;
  const int w = tid >> 6;
  const int lane = tid & 63;
  const int l4 = lane << 2;

  __shared__ float hrows[16][256];  // 16 KB
  __shared__ float xs[256];
  __shared__ float pp[4][256];      // 4 KB

  // Parallel prefetch of the 16 aggregate-input rows, scaled by 0.25.
  const float* base = h1 + (size_t)j * 4096;
#pragma unroll
  for (int t = 0; t < 4; ++t) {
    const int idx = (t << 8) + tid;        // 0..1023 float4 slots
    const int r = idx >> 6;
    const int c4 = (idx & 63) << 2;
    float4 f = *reinterpret_cast<const float4*>(base + r * 256 + c4);
    f.x *= 0.25f; f.y *= 0.25f; f.z *= 0.25f; f.w *= 0.25f;
    *reinterpret_cast<float4*>(&hrows[r][c4]) = f;
  }
  __syncthreads();

  float4 x = make_float4(0.f, 0.f, 0.f, 0.f);
  if (w == 0) {
    x = *reinterpret_cast<const float4*>(&hrows[0][l4]);
#pragma unroll 1
    for (int kk = 1; kk < 16; ++kk) {
      const float4 y = *reinterpret_cast<const float4*>(&hrows[kk][l4]);
      x = mobius_step(x, y);
    }
    *reinterpret_cast<float4*>(&xs[l4]) = x;
  }
  __syncthreads();

  // mobius_matvec(x, W2): wave w accumulates d in [64w, 64w+64).
  {
    float4 p = make_float4(0.f, 0.f, 0.f, 0.f);
    const int dbase = w << 6;
    for (int d = 0; d < 64; ++d) {
      const float xd = xs[dbase + d];
      const float4 wv =
          *reinterpret_cast<const float4*>(W2 + (size_t)(dbase + d) * 256 + l4);
      p.x = fmaf(xd, wv.x, p.x);
      p.y = fmaf(xd, wv.y, p.y);
      p.z = fmaf(xd, wv.z, p.z);
      p.w = fmaf(xd, wv.w, p.w);
    }
    *reinterpret_cast<float4*>(&pp[w][l4]) = p;
  }
  __syncthreads();

  if (w == 0) {
    float4 mx;
    mx.x = pp[0][l4 + 0] + pp[1][l4 + 0] + pp[2][l4 + 0] + pp[3][l4 + 0];
    mx.y = pp[0][l4 + 1] + pp[1][l4 + 1] + pp[2][l4 + 1] + pp[3][l4 + 1];
    mx.z = pp[0][l4 + 2] + pp[1][l4 + 2] + pp[2][l4 + 2] + pp[3][l4 + 2];
    mx.w = pp[0][l4 + 3] + pp[1][l4 + 3] + pp[2][l4 + 3] + pp[3][l4 + 3];
    {
      float px = wsum(dot4(x, x));
      float pm = wsum(dot4(mx, mx));
      float xn = fminf(fmaxf(sqrtf(px), EPSF), MAXNF);
      float mxn = fmaxf(sqrtf(pm), EPSF);
      float s = tanhf(mxn / xn * atanhf(xn)) / mxn;
      s *= 0.25f;  // rst * norm
      x.x = s * mx.x; x.y = s * mx.y; x.z = s * mx.z; x.w = s * mx.w;
    }
    {
      const float4 b = *reinterpret_cast<const float4*>(b2 + l4);
      x = mobius_step(x, b);
    }
    float pn = wsum(dot4(x, x));
    float yn = fminf(fmaxf(sqrtf(pn), EPSF), MAXNF);
    float s = atanhf(yn) / yn;
    float4 v;
    v.x = fmaxf(s * x.x, 0.f);
    v.y = fmaxf(s * x.y, 0.f);
    v.z = fmaxf(s * x.z, 0.f);
    v.w = fmaxf(s * x.w, 0.f);
    float pv = wsum(dot4(v, v));
    float vn = fmaxf(sqrtf(pv), EPSF);
    float s2 = tanhf(vn) / vn;
    float4 h;
    h.x = s2 * v.x; h.y = s2 * v.y; h.z = s2 * v.z; h.w = s2 * v.w;

    // Layer 3: mx2[o] = sum_d h[d] * Wl[o][d], o = lane.
    *reinterpret_cast<float4*>(&xs[l4]) = h;
    float m = 0.f;
    for (int d = 0; d < 256; d += 4) {
      const float4 wv =
          *reinterpret_cast<const float4*>(Wl + (size_t)lane * 256 + d);
      m = fmaf(wv.x, xs[d + 0], m);
      m = fmaf(wv.y, xs[d + 1], m);
      m = fmaf(wv.z, xs[d + 2], m);
      m = fmaf(wv.w, xs[d + 3], m);
    }
    float ph = wsum(dot4(h, h));
    float pmm = wsum(m * m);
    float hn = fminf(fmaxf(sqrtf(ph), EPSF), MAXNF);
    float mn = fmaxf(sqrtf(pmm), EPSF);
    float sc = tanhf(mn / hn * atanhf(hn)) / mn;
    float mo = sc * m;
    float bo = bl[lane];
    float pxx = wsum(mo * mo);
    float pbb = wsum(bo * bo);
    float pxb = wsum(mo * bo);
    float cx = 1.f + 2.f * pxb + pbb;
    float cy = 1.f - pxx;
    float inv = 1.f / fmaxf(1.f + 2.f * pxb + pxx * pbb, EPSF);
    out[j * 64 + lane] = (cx * mo + cy * bo) * inv;
  }
}

extern "C" void kernel_launch(void* const* d_in, const int* in_sizes, int n_in,
                              void* d_out, int out_size, void* d_ws,
                              size_t ws_size, hipStream_t stream) {
  const float* features = (const float*)d_in[0];
  const float* W1 = (const float*)d_in[1];
  const float* b1 = (const float*)d_in[2];
  const float* W2 = (const float*)d_in[3];
  const float* b2 = (const float*)d_in[4];
  const float* Wl = (const float*)d_in[5];
  const float* bl = (const float*)d_in[6];
  const int* src_idx = (const int*)d_in[7];
  const int* to_fetch = (const int*)d_in[8];
  float* out = (float*)d_out;

  float* h1 = (float*)d_ws;  // 1 MB
  unsigned short* whi = (unsigned short*)((char*)d_ws + (1u << 20));   // 256 KB
  unsigned short* wlo = (unsigned short*)((char*)d_ws + (1u << 20) + (1u << 18));

  k0_pack<<<64, 256, 0, stream>>>(W1, whi, wlo);
  k1_h1<<<512, 256, 0, stream>>>(features, whi, wlo, b1, src_idx, to_fetch, h1);
  k2_out<<<64, 256, 0, stream>>>(h1, W2, b2, Wl, bl, out);
}

// Round 10
// 52.731 us; speedup vs baseline: 6.6590x; 1.0190x over previous
//
#include <hip/hip_runtime.h>
#include <math.h>

#define EPSF 1e-7f
#define MAXNF (1.0f - 1e-5f)

typedef __attribute__((ext_vector_type(8))) short short8;
typedef __attribute__((ext_vector_type(4))) float f32x4;

union Pun8 { unsigned short u[8]; short8 s; };

static __device__ __forceinline__ unsigned short f2bf_rn(float f) {
  union { float f; unsigned u; } v;
  v.f = f;
  unsigned r = v.u + 0x7fff + ((v.u >> 16) & 1);  // RNE; inputs are finite
  return (unsigned short)(r >> 16);
}
static __device__ __forceinline__ float bf2f(unsigned short h) {
  union { unsigned u; float f; } v;
  v.u = ((unsigned)h) << 16;
  return v.f;
}

__device__ __forceinline__ float wsum(float v) {
#pragma unroll
  for (int off = 32; off >= 1; off >>= 1) v += __shfl_xor(v, off, 64);
  return v;
}
__device__ __forceinline__ float hsum16(float v) {
#pragma unroll
  for (int off = 8; off >= 1; off >>= 1) v += __shfl_xor(v, off, 64);
  return v;
}
__device__ __forceinline__ float dot4(const float4 a, const float4 b) {
  return a.x * b.x + a.y * b.y + a.z * b.z + a.w * b.w;
}
__device__ __forceinline__ float4 mobius_step(const float4 x, const float4 y) {
  float px = wsum(dot4(x, x));
  float py = wsum(dot4(y, y));
  float pxy = wsum(dot4(x, y));
  float cx = 1.f + 2.f * pxy + py;
  float cy = 1.f - px;
  float inv = 1.f / fmaxf(1.f + 2.f * pxy + px * py, EPSF);
  float4 r;
  r.x = (cx * x.x + cy * y.x) * inv;
  r.y = (cx * x.y + cy * y.y) * inv;
  r.z = (cx * x.z + cy * y.z) * inv;
  r.w = (cx * x.w + cy * y.w) * inv;
  return r;
}

// k0: pack W1 (512x256 f32) into bf16 hi/lo planes in MFMA B-fragment order
// (unchanged): element (s,t,lane,j) = W1[s*32+(lane>>4)*8+j][t*16+(lane&15)]
// at short index ((s*16+t)*64+lane)*8 + j.
__global__ __launch_bounds__(256) void
k0_pack(const float* __restrict__ W1, unsigned short* __restrict__ hi,
        unsigned short* __restrict__ lo) {
  const int id = blockIdx.x * 256 + threadIdx.x;  // 0..16383
  const int s = id >> 10;
  const int t = (id >> 6) & 15;
  const int l = id & 63;
  const int n = t * 16 + (l & 15);
  const int k0 = s * 32 + ((l >> 4) << 3);
  Pun8 ph, pl;
#pragma unroll
  for (int jj = 0; jj < 8; ++jj) {
    float wv = W1[(k0 + jj) * 256 + n];
    unsigned short hb = f2bf_rn(wv);
    ph.u[jj] = hb;
    pl.u[jj] = f2bf_rn(wv - bf2f(hb));
  }
  *reinterpret_cast<short8*>(hi + id * 8) = ph.s;
  *reinterpret_cast<short8*>(lo + id * 8) = pl.s;
}

// k1: 256 blocks (1/CU), 512 threads = 8 waves (2/SIMD). Each block = 4
// (j,k) pairs = 64 gathered rows in LDS (bf16 hi/lo, XOR-swizzled). Wave w
// owns n-tiles {2w, 2w+1} for ALL 4 pairs: B frags reused 4x -> per-CU
// B VMEM instr halves vs round 8; 24 MFMA per (A,B) set covers L2 latency.
__global__ __launch_bounds__(512, 1) void
k1_h1(const float* __restrict__ features, const unsigned short* __restrict__ bhi,
      const unsigned short* __restrict__ blo, const float* __restrict__ b1,
      const int* __restrict__ src_idx, const int* __restrict__ to_fetch,
      float* __restrict__ h1) {
  const int b4 = blockIdx.x << 2;  // first pair index of this block
  const int tid = threadIdx.x;
  const int w = tid >> 6;          // 0..7
  const int lane = tid & 63;
  const int g = lane >> 4;
  const int r16 = lane & 15;

  __shared__ __align__(16) unsigned short aH[64 * 512];  // 64 KB
  __shared__ __align__(16) unsigned short aL[64 * 512];  // 64 KB
  __shared__ float s_msp[8][64];
  __shared__ float s_fs2[64], s_srow[64];
  __shared__ int s_anode[4];
  __shared__ int s_vn[64];

  if (tid < 4) {
    const int pair = b4 + tid;
    const int jj = pair >> 4, kk = pair & 15;
    s_anode[tid] = src_idx[(to_fetch[jj] + (jj << 10)) * 16 + kk];
  }
  __syncthreads();
  if (tid < 64) s_vn[tid] = src_idx[s_anode[tid >> 4] * 16 + (tid & 15)];
  __syncthreads();

  // Stage: wave w stages rows w*8..w*8+7, two batches of 4 rows with all
  // global loads issued before any consumption.
#pragma unroll
  for (int batch = 0; batch < 2; ++batch) {
    float4 f0[4], f1[4];
    const int rb = (w << 3) + (batch << 2);
#pragma unroll
    for (int i = 0; i < 4; ++i) {
      const float* rp = features + (size_t)s_vn[rb + i] * 512 + lane * 8;
      f0[i] = *reinterpret_cast<const float4*>(rp);
      f1[i] = *reinterpret_cast<const float4*>(rp + 4);
    }
#pragma unroll
    for (int i = 0; i < 4; ++i) {
      const int r = rb + i;
      const float fv[8] = {f0[i].x, f0[i].y, f0[i].z, f0[i].w,
                           f1[i].x, f1[i].y, f1[i].z, f1[i].w};
      Pun8 ph, pl;
      float ss = 0.f;
#pragma unroll
      for (int q = 0; q < 8; ++q) {
        ss = fmaf(fv[q], fv[q], ss);
        unsigned short hb = f2bf_rn(fv[q]);
        ph.u[q] = hb;
        pl.u[q] = f2bf_rn(fv[q] - bf2f(hb));
      }
      const int off = r * 512 + ((lane * 8) ^ ((r & 7) * 8));
      *reinterpret_cast<short8*>(&aH[off]) = ph.s;
      *reinterpret_cast<short8*>(&aL[off]) = pl.s;
      ss = wsum(ss);
      if (lane == 0) s_fs2[r] = ss;
    }
  }
  __syncthreads();

  const int g8 = g * 8;
  const int sw = (r16 & 7) * 8;
  const int tbase = w * 2;  // wave's first n-tile
  const short8* Bh = reinterpret_cast<const short8*>(bhi);
  const short8* Bl = reinterpret_cast<const short8*>(blo);

  f32x4 acc[4][2];  // [pair][ntile]
#pragma unroll
  for (int p = 0; p < 4; ++p)
#pragma unroll
    for (int i = 0; i < 2; ++i) acc[p][i] = (f32x4){0.f, 0.f, 0.f, 0.f};

  short8 A0[4][2], A1[4][2];  // [pair][hi/lo]
  short8 B0[2][2], B1[2][2];  // [ntile][hi/lo]

#define LOADA(AR, S)                                                          \
  {                                                                           \
    const int s_ = (S)&15;                                                    \
    _Pragma("unroll") for (int p_ = 0; p_ < 4; ++p_) {                        \
      const int o_ = ((p_ << 4) + r16) * 512 + (((s_ << 5) + g8) ^ sw);       \
      AR[p_][0] = *reinterpret_cast<const short8*>(&aH[o_]);                  \
      AR[p_][1] = *reinterpret_cast<const short8*>(&aL[o_]);                  \
    }                                                                         \
  }
#define LOADB(BR, S)                                                          \
  {                                                                           \
    const int s_ = (S)&15;                                                    \
    _Pragma("unroll") for (int i_ = 0; i_ < 2; ++i_) {                        \
      const int idx_ = ((s_ << 4) + tbase + i_) * 64 + lane;                  \
      BR[i_][0] = Bh[idx_];                                                   \
      BR[i_][1] = Bl[idx_];                                                   \
    }                                                                         \
  }
#define MFMAALL(AR, BR)                                                       \
  _Pragma("unroll") for (int p_ = 0; p_ < 4; ++p_)                            \
      _Pragma("unroll") for (int i_ = 0; i_ < 2; ++i_) acc[p_][i_] =          \
      __builtin_amdgcn_mfma_f32_16x16x32_bf16(AR[p_][0], BR[i_][0],           \
                                              acc[p_][i_], 0, 0, 0);          \
  _Pragma("unroll") for (int p_ = 0; p_ < 4; ++p_)                            \
      _Pragma("unroll") for (int i_ = 0; i_ < 2; ++i_) acc[p_][i_] =          \
      __builtin_amdgcn_mfma_f32_16x16x32_bf16(AR[p_][0], BR[i_][1],           \
                                              acc[p_][i_], 0, 0, 0);          \
  _Pragma("unroll") for (int p_ = 0; p_ < 4; ++p_)                            \
      _Pragma("unroll") for (int i_ = 0; i_ < 2; ++i_) acc[p_][i_] =          \
      __builtin_amdgcn_mfma_f32_16x16x32_bf16(AR[p_][1], BR[i_][0],           \
                                              acc[p_][i_], 0, 0, 0);

  LOADA(A0, 0)
  LOADB(B0, 0)
#pragma unroll 1
  for (int s = 0; s < 16; s += 2) {
    LOADB(B1, s + 1)
    LOADA(A1, s + 1)
    MFMAALL(A0, B0)
    LOADB(B0, s + 2)
    LOADA(A0, s + 2)
    MFMAALL(A1, B1)
  }

  // Row norms of mx: lane covers (pair p, rows g*4+reg) over its 2 n-tiles
  // (32 cols); hsum16 reduces over col-lanes; cross-wave sum in LDS.
#pragma unroll
  for (int p = 0; p < 4; ++p) {
    float rs[4];
#pragma unroll
    for (int reg = 0; reg < 4; ++reg) {
      float v = fmaf(acc[p][0][reg], acc[p][0][reg],
                     acc[p][1][reg] * acc[p][1][reg]);
      rs[reg] = hsum16(v);
    }
    if (r16 == 0) {
#pragma unroll
      for (int reg = 0; reg < 4; ++reg)
        s_msp[w][(p << 4) + (g << 2) + reg] = rs[reg];
    }
  }
  __syncthreads();
  if (tid < 64) {
    float ms2 = 0.f;
#pragma unroll
    for (int ww = 0; ww < 8; ++ww) ms2 += s_msp[ww][tid];
    const float xn = fminf(fmaxf(0.25f * sqrtf(s_fs2[tid]), EPSF), MAXNF);
    const float mxn = fmaxf(0.25f * sqrtf(ms2), EPSF);
    s_srow[tid] = tanhf(mxn / xn * atanhf(xn)) * 0.25f / mxn;
  }
  __syncthreads();

  // Scaled transformed rows overlay the (now dead) aH plane: 64x256 f32.
  float(*trow)[256] = reinterpret_cast<float(*)[256]>(&aH[0]);
#pragma unroll
  for (int p = 0; p < 4; ++p) {
#pragma unroll
    for (int i = 0; i < 2; ++i) {
      const int n = ((tbase + i) << 4) + r16;
#pragma unroll
      for (int reg = 0; reg < 4; ++reg) {
        const int row = (p << 4) + (g << 2) + reg;
        trow[row][n] = acc[p][i][reg] * s_srow[row];
      }
    }
  }
  __syncthreads();

  // Chained mobius_add: waves 0..3 each process one pair.
  if (w < 4) {
    const int l4 = lane << 2;
    float4 x = *reinterpret_cast<const float4*>(&trow[w * 16][l4]);
#pragma unroll 1
    for (int kk = 1; kk < 16; ++kk) {
      const float4 y = *reinterpret_cast<const float4*>(&trow[w * 16 + kk][l4]);
      x = mobius_step(x, y);
    }
    x.x *= 0.25f; x.y *= 0.25f; x.z *= 0.25f; x.w *= 0.25f;
    {
      const float4 b = *reinterpret_cast<const float4*>(b1 + l4);
      x = mobius_step(x, b);
    }
    float pn = wsum(dot4(x, x));
    float yn = fminf(fmaxf(sqrtf(pn), EPSF), MAXNF);
    float s = atanhf(yn) / yn;
    float4 v;
    v.x = fmaxf(s * x.x, 0.f);
    v.y = fmaxf(s * x.y, 0.f);
    v.z = fmaxf(s * x.z, 0.f);
    v.w = fmaxf(s * x.w, 0.f);
    float pv = wsum(dot4(v, v));
    float vn = fmaxf(sqrtf(pv), EPSF);
    float s2 = tanhf(vn) / vn;
    float4 h;
    h.x = s2 * v.x;
    h.y = s2 * v.y;
    h.z = s2 * v.z;
    h.w = s2 * v.w;
    *reinterpret_cast<float4*>(h1 + (size_t)(b4 + w) * 256 + l4) = h;
  }
#undef LOADA
#undef LOADB
#undef MFMAALL
}

// Kernel 2: 64 blocks x 256 threads (unchanged from round 9).
__global__ __launch_bounds__(256) void
k2_out(const float* __restrict__ h1, const float* __restrict__ W2,
       const float* __restrict__ b2, const float* __restrict__ Wl,
       const float* __restrict__ bl, float* __restrict__ out) {
  const int j = blockIdx.x;
  const int tid = threadIdx.x;
  const int w = tid >> 6;
  const int lane = tid & 63;
  const int l4 = lane << 2;

  __shared__ float hrows[16][256];  // 16 KB
  __shared__ float xs[256];
  __shared__ float pp[4][256];      // 4 KB

  const float* base = h1 + (size_t)j * 4096;
#pragma unroll
  for (int t = 0; t < 4; ++t) {
    const int idx = (t << 8) + tid;        // 0..1023 float4 slots
    const int r = idx >> 6;
    const int c4 = (idx & 63) << 2;
    float4 f = *reinterpret_cast<const float4*>(base + r * 256 + c4);
    f.x *= 0.25f; f.y *= 0.25f; f.z *= 0.25f; f.w *= 0.25f;
    *reinterpret_cast<float4*>(&hrows[r][c4]) = f;
  }
  __syncthreads();

  float4 x = make_float4(0.f, 0.f, 0.f, 0.f);
  if (w == 0) {
    x = *reinterpret_cast<const float4*>(&hrows[0][l4]);
#pragma unroll 1
    for (int kk = 1; kk < 16; ++kk) {
      const float4 y = *reinterpret_cast<const float4*>(&hrows[kk][l4]);
      x = mobius_step(x, y);
    }
    *reinterpret_cast<float4*>(&xs[l4]) = x;
  }
  __syncthreads();

  // mobius_matvec(x, W2): wave w accumulates d in [64w, 64w+64).
  {
    float4 p = make_float4(0.f, 0.f, 0.f, 0.f);
    const int dbase = w << 6;
    for (int d = 0; d < 64; ++d) {
      const float xd = xs[dbase + d];
      const float4 wv =
          *reinterpret_cast<const float4*>(W2 + (size_t)(dbase + d) * 256 + l4);
      p.x = fmaf(xd, wv.x, p.x);
      p.y = fmaf(xd, wv.y, p.y);
      p.z = fmaf(xd, wv.z, p.z);
      p.w = fmaf(xd, wv.w, p.w);
    }
    *reinterpret_cast<float4*>(&pp[w][l4]) = p;
  }
  __syncthreads();

  if (w == 0) {
    float4 mx;
    mx.x = pp[0][l4 + 0] + pp[1][l4 + 0] + pp[2][l4 + 0] + pp[3][l4 + 0];
    mx.y = pp[0][l4 + 1] + pp[1][l4 + 1] + pp[2][l4 + 1] + pp[3][l4 + 1];
    mx.z = pp[0][l4 + 2] + pp[1][l4 + 2] + pp[2][l4 + 2] + pp[3][l4 + 2];
    mx.w = pp[0][l4 + 3] + pp[1][l4 + 3] + pp[2][l4 + 3] + pp[3][l4 + 3];
    {
      float px = wsum(dot4(x, x));
      float pm = wsum(dot4(mx, mx));
      float xn = fminf(fmaxf(sqrtf(px), EPSF), MAXNF);
      float mxn = fmaxf(sqrtf(pm), EPSF);
      float s = tanhf(mxn / xn * atanhf(xn)) / mxn;
      s *= 0.25f;  // rst * norm
      x.x = s * mx.x; x.y = s * mx.y; x.z = s * mx.z; x.w = s * mx.w;
    }
    {
      const float4 b = *reinterpret_cast<const float4*>(b2 + l4);
      x = mobius_step(x, b);
    }
    float pn = wsum(dot4(x, x));
    float yn = fminf(fmaxf(sqrtf(pn), EPSF), MAXNF);
    float s = atanhf(yn) / yn;
    float4 v;
    v.x = fmaxf(s * x.x, 0.f);
    v.y = fmaxf(s * x.y, 0.f);
    v.z = fmaxf(s * x.z, 0.f);
    v.w = fmaxf(s * x.w, 0.f);
    float pv = wsum(dot4(v, v));
    float vn = fmaxf(sqrtf(pv), EPSF);
    float s2 = tanhf(vn) / vn;
    float4 h;
    h.x = s2 * v.x; h.y = s2 * v.y; h.z = s2 * v.z; h.w = s2 * v.w;

    *reinterpret_cast<float4*>(&xs[l4]) = h;
    float m = 0.f;
    for (int d = 0; d < 256; d += 4) {
      const float4 wv =
          *reinterpret_cast<const float4*>(Wl + (size_t)lane * 256 + d);
      m = fmaf(wv.x, xs[d + 0], m);
      m = fmaf(wv.y, xs[d + 1], m);
      m = fmaf(wv.z, xs[d + 2], m);
      m = fmaf(wv.w, xs[d + 3], m);
    }
    float ph = wsum(dot4(h, h));
    float pmm = wsum(m * m);
    float hn = fminf(fmaxf(sqrtf(ph), EPSF), MAXNF);
    float mn = fmaxf(sqrtf(pmm), EPSF);
    float sc = tanhf(mn / hn * atanhf(hn)) / mn;
    float mo = sc * m;
    float bo = bl[lane];
    float pxx = wsum(mo * mo);
    float pbb = wsum(bo * bo);
    float pxb = wsum(mo * bo);
    float cx = 1.f + 2.f * pxb + pbb;
    float cy = 1.f - pxx;
    float inv = 1.f / fmaxf(1.f + 2.f * pxb + pxx * pbb, EPSF);
    out[j * 64 + lane] = (cx * mo + cy * bo) * inv;
  }
}

extern "C" void kernel_launch(void* const* d_in, const int* in_sizes, int n_in,
                              void* d_out, int out_size, void* d_ws,
                              size_t ws_size, hipStream_t stream) {
  const float* features = (const float*)d_in[0];
  const float* W1 = (const float*)d_in[1];
  const float* b1 = (const float*)d_in[2];
  const float* W2 = (const float*)d_in[3];
  const float* b2 = (const float*)d_in[4];
  const float* Wl = (const float*)d_in[5];
  const float* bl = (const float*)d_in[6];
  const int* src_idx = (const int*)d_in[7];
  const int* to_fetch = (const int*)d_in[8];
  float* out = (float*)d_out;

  float* h1 = (float*)d_ws;  // 1 MB
  unsigned short* whi = (unsigned short*)((char*)d_ws + (1u << 20));   // 256 KB
  unsigned short* wlo = (unsigned short*)((char*)d_ws + (1u << 20) + (1u << 18));

  k0_pack<<<64, 256, 0, stream>>>(W1, whi, wlo);
  k1_h1<<<256, 512, 0, stream>>>(features, whi, wlo, b1, src_idx, to_fetch, h1);
  k2_out<<<64, 256, 0, stream>>>(h1, W2, b2, Wl, bl, out);
}

// Round 11
// 45.912 us; speedup vs baseline: 7.6479x; 1.1485x over previous
//
#include <hip/hip_runtime.h>
#include <math.h>

#define EPSF 1e-7f
#define MAXNF (1.0f - 1e-5f)

typedef __attribute__((ext_vector_type(8))) short short8;
typedef __attribute__((ext_vector_type(4))) float f32x4;

union Pun8 { unsigned short u[8]; short8 s; };

static __device__ __forceinline__ unsigned short f2bf_rn(float f) {
  union { float f; unsigned u; } v;
  v.f = f;
  unsigned r = v.u + 0x7fff + ((v.u >> 16) & 1);  // RNE; inputs are finite
  return (unsigned short)(r >> 16);
}
static __device__ __forceinline__ float bf2f(unsigned short h) {
  union { unsigned u; float f; } v;
  v.u = ((unsigned)h) << 16;
  return v.f;
}

// DPP-based reductions: VALU-pipe cross-lane adds (~10 cyc) instead of
// ds_bpermute-based __shfl (~100 cyc latency each).
template <int CTRL>
static __device__ __forceinline__ float dpp_add(float v) {
  int s = __builtin_amdgcn_update_dpp(0, __float_as_int(v), CTRL, 0xf, 0xf,
                                      true);
  return v + __int_as_float(s);
}
// Full-wave sum, wave-uniform result (readlane -> SGPR broadcast).
static __device__ __forceinline__ float wsum(float v) {
  v = dpp_add<0x111>(v);  // row_shr:1
  v = dpp_add<0x112>(v);  // row_shr:2
  v = dpp_add<0x114>(v);  // row_shr:4
  v = dpp_add<0x118>(v);  // row_shr:8
  v = dpp_add<0x142>(v);  // row_bcast:15
  v = dpp_add<0x143>(v);  // row_bcast:31
  return __int_as_float(__builtin_amdgcn_readlane(__float_as_int(v), 63));
}
// Per-16-lane-group sum; FULL sum valid only in lane (lane&15)==15.
static __device__ __forceinline__ float hsum16_t(float v) {
  v = dpp_add<0x111>(v);
  v = dpp_add<0x112>(v);
  v = dpp_add<0x114>(v);
  v = dpp_add<0x118>(v);
  return v;
}

__device__ __forceinline__ float dot4(const float4 a, const float4 b) {
  return a.x * b.x + a.y * b.y + a.z * b.z + a.w * b.w;
}
__device__ __forceinline__ float4 mobius_step(const float4 x, const float4 y) {
  float px = wsum(dot4(x, x));
  float py = wsum(dot4(y, y));
  float pxy = wsum(dot4(x, y));
  float cx = 1.f + 2.f * pxy + py;
  float cy = 1.f - px;
  float inv = 1.f / fmaxf(1.f + 2.f * pxy + px * py, EPSF);
  float4 r;
  r.x = (cx * x.x + cy * y.x) * inv;
  r.y = (cx * x.y + cy * y.y) * inv;
  r.z = (cx * x.z + cy * y.z) * inv;
  r.w = (cx * x.w + cy * y.w) * inv;
  return r;
}

// k0: pack W1 (512x256 f32) into bf16 hi/lo planes in MFMA B-fragment order
// (unchanged): element (s,t,lane,j) = W1[s*32+(lane>>4)*8+j][t*16+(lane&15)]
// at short index ((s*16+t)*64+lane)*8 + j.
__global__ __launch_bounds__(256) void
k0_pack(const float* __restrict__ W1, unsigned short* __restrict__ hi,
        unsigned short* __restrict__ lo) {
  const int id = blockIdx.x * 256 + threadIdx.x;  // 0..16383
  const int s = id >> 10;
  const int t = (id >> 6) & 15;
  const int l = id & 63;
  const int n = t * 16 + (l & 15);
  const int k0 = s * 32 + ((l >> 4) << 3);
  Pun8 ph, pl;
#pragma unroll
  for (int jj = 0; jj < 8; ++jj) {
    float wv = W1[(k0 + jj) * 256 + n];
    unsigned short hb = f2bf_rn(wv);
    ph.u[jj] = hb;
    pl.u[jj] = f2bf_rn(wv - bf2f(hb));
  }
  *reinterpret_cast<short8*>(hi + id * 8) = ph.s;
  *reinterpret_cast<short8*>(lo + id * 8) = pl.s;
}

// k1: 256 blocks (1/CU), 512 threads = 8 waves. 4 pairs/block (unchanged
// structure from round 10; reductions now DPP-based).
__global__ __launch_bounds__(512, 1) void
k1_h1(const float* __restrict__ features, const unsigned short* __restrict__ bhi,
      const unsigned short* __restrict__ blo, const float* __restrict__ b1,
      const int* __restrict__ src_idx, const int* __restrict__ to_fetch,
      float* __restrict__ h1) {
  const int b4 = blockIdx.x << 2;  // first pair index of this block
  const int tid = threadIdx.x;
  const int w = tid >> 6;          // 0..7
  const int lane = tid & 63;
  const int g = lane >> 4;
  const int r16 = lane & 15;

  __shared__ __align__(16) unsigned short aH[64 * 512];  // 64 KB
  __shared__ __align__(16) unsigned short aL[64 * 512];  // 64 KB
  __shared__ float s_msp[8][64];
  __shared__ float s_fs2[64], s_srow[64];
  __shared__ int s_anode[4];
  __shared__ int s_vn[64];

  if (tid < 4) {
    const int pair = b4 + tid;
    const int jj = pair >> 4, kk = pair & 15;
    s_anode[tid] = src_idx[(to_fetch[jj] + (jj << 10)) * 16 + kk];
  }
  __syncthreads();
  if (tid < 64) s_vn[tid] = src_idx[s_anode[tid >> 4] * 16 + (tid & 15)];
  __syncthreads();

  // Stage: wave w stages rows w*8..w*8+7, two batches of 4 rows.
#pragma unroll
  for (int batch = 0; batch < 2; ++batch) {
    float4 f0[4], f1[4];
    const int rb = (w << 3) + (batch << 2);
#pragma unroll
    for (int i = 0; i < 4; ++i) {
      const float* rp = features + (size_t)s_vn[rb + i] * 512 + lane * 8;
      f0[i] = *reinterpret_cast<const float4*>(rp);
      f1[i] = *reinterpret_cast<const float4*>(rp + 4);
    }
#pragma unroll
    for (int i = 0; i < 4; ++i) {
      const int r = rb + i;
      const float fv[8] = {f0[i].x, f0[i].y, f0[i].z, f0[i].w,
                           f1[i].x, f1[i].y, f1[i].z, f1[i].w};
      Pun8 ph, pl;
      float ss = 0.f;
#pragma unroll
      for (int q = 0; q < 8; ++q) {
        ss = fmaf(fv[q], fv[q], ss);
        unsigned short hb = f2bf_rn(fv[q]);
        ph.u[q] = hb;
        pl.u[q] = f2bf_rn(fv[q] - bf2f(hb));
      }
      const int off = r * 512 + ((lane * 8) ^ ((r & 7) * 8));
      *reinterpret_cast<short8*>(&aH[off]) = ph.s;
      *reinterpret_cast<short8*>(&aL[off]) = pl.s;
      ss = wsum(ss);  // wave-uniform
      if (lane == 0) s_fs2[r] = ss;
    }
  }
  __syncthreads();

  const int g8 = g * 8;
  const int sw = (r16 & 7) * 8;
  const int tbase = w * 2;  // wave's first n-tile
  const short8* Bh = reinterpret_cast<const short8*>(bhi);
  const short8* Bl = reinterpret_cast<const short8*>(blo);

  f32x4 acc[4][2];  // [pair][ntile]
#pragma unroll
  for (int p = 0; p < 4; ++p)
#pragma unroll
    for (int i = 0; i < 2; ++i) acc[p][i] = (f32x4){0.f, 0.f, 0.f, 0.f};

  short8 A0[4][2], A1[4][2];  // [pair][hi/lo]
  short8 B0[2][2], B1[2][2];  // [ntile][hi/lo]

#define LOADA(AR, S)                                                          \
  {                                                                           \
    const int s_ = (S)&15;                                                    \
    _Pragma("unroll") for (int p_ = 0; p_ < 4; ++p_) {                        \
      const int o_ = ((p_ << 4) + r16) * 512 + (((s_ << 5) + g8) ^ sw);       \
      AR[p_][0] = *reinterpret_cast<const short8*>(&aH[o_]);                  \
      AR[p_][1] = *reinterpret_cast<const short8*>(&aL[o_]);                  \
    }                                                                         \
  }
#define LOADB(BR, S)                                                          \
  {                                                                           \
    const int s_ = (S)&15;                                                    \
    _Pragma("unroll") for (int i_ = 0; i_ < 2; ++i_) {                        \
      const int idx_ = ((s_ << 4) + tbase + i_) * 64 + lane;                  \
      BR[i_][0] = Bh[idx_];                                                   \
      BR[i_][1] = Bl[idx_];                                                   \
    }                                                                         \
  }
#define MFMAALL(AR, BR)                                                       \
  _Pragma("unroll") for (int p_ = 0; p_ < 4; ++p_)                            \
      _Pragma("unroll") for (int i_ = 0; i_ < 2; ++i_) acc[p_][i_] =          \
      __builtin_amdgcn_mfma_f32_16x16x32_bf16(AR[p_][0], BR[i_][0],           \
                                              acc[p_][i_], 0, 0, 0);          \
  _Pragma("unroll") for (int p_ = 0; p_ < 4; ++p_)                            \
      _Pragma("unroll") for (int i_ = 0; i_ < 2; ++i_) acc[p_][i_] =          \
      __builtin_amdgcn_mfma_f32_16x16x32_bf16(AR[p_][0], BR[i_][1],           \
                                              acc[p_][i_], 0, 0, 0);          \
  _Pragma("unroll") for (int p_ = 0; p_ < 4; ++p_)                            \
      _Pragma("unroll") for (int i_ = 0; i_ < 2; ++i_) acc[p_][i_] =          \
      __builtin_amdgcn_mfma_f32_16x16x32_bf16(AR[p_][1], BR[i_][0],           \
                                              acc[p_][i_], 0, 0, 0);

  LOADA(A0, 0)
  LOADB(B0, 0)
#pragma unroll 1
  for (int s = 0; s < 16; s += 2) {
    LOADB(B1, s + 1)
    LOADA(A1, s + 1)
    MFMAALL(A0, B0)
    LOADB(B0, s + 2)
    LOADA(A0, s + 2)
    MFMAALL(A1, B1)
  }

  // Row norms of mx: per-lane partial over 2 n-tiles, DPP 16-group reduce
  // (sum valid in lane r16==15), cross-wave sum in LDS.
#pragma unroll
  for (int p = 0; p < 4; ++p) {
    float rs[4];
#pragma unroll
    for (int reg = 0; reg < 4; ++reg) {
      float v = fmaf(acc[p][0][reg], acc[p][0][reg],
                     acc[p][1][reg] * acc[p][1][reg]);
      rs[reg] = hsum16_t(v);
    }
    if (r16 == 15) {
#pragma unroll
      for (int reg = 0; reg < 4; ++reg)
        s_msp[w][(p << 4) + (g << 2) + reg] = rs[reg];
    }
  }
  __syncthreads();
  if (tid < 64) {
    float ms2 = 0.f;
#pragma unroll
    for (int ww = 0; ww < 8; ++ww) ms2 += s_msp[ww][tid];
    const float xn = fminf(fmaxf(0.25f * sqrtf(s_fs2[tid]), EPSF), MAXNF);
    const float mxn = fmaxf(0.25f * sqrtf(ms2), EPSF);
    s_srow[tid] = tanhf(mxn / xn * atanhf(xn)) * 0.25f / mxn;
  }
  __syncthreads();

  // Scaled transformed rows overlay the (now dead) aH plane: 64x256 f32.
  float(*trow)[256] = reinterpret_cast<float(*)[256]>(&aH[0]);
#pragma unroll
  for (int p = 0; p < 4; ++p) {
#pragma unroll
    for (int i = 0; i < 2; ++i) {
      const int n = ((tbase + i) << 4) + r16;
#pragma unroll
      for (int reg = 0; reg < 4; ++reg) {
        const int row = (p << 4) + (g << 2) + reg;
        trow[row][n] = acc[p][i][reg] * s_srow[row];
      }
    }
  }
  __syncthreads();

  // Chained mobius_add: waves 0..3 each process one pair.
  if (w < 4) {
    const int l4 = lane << 2;
    float4 x = *reinterpret_cast<const float4*>(&trow[w * 16][l4]);
#pragma unroll 1
    for (int kk = 1; kk < 16; ++kk) {
      const float4 y = *reinterpret_cast<const float4*>(&trow[w * 16 + kk][l4]);
      x = mobius_step(x, y);
    }
    x.x *= 0.25f; x.y *= 0.25f; x.z *= 0.25f; x.w *= 0.25f;
    {
      const float4 b = *reinterpret_cast<const float4*>(b1 + l4);
      x = mobius_step(x, b);
    }
    float pn = wsum(dot4(x, x));
    float yn = fminf(fmaxf(sqrtf(pn), EPSF), MAXNF);
    float s = atanhf(yn) / yn;
    float4 v;
    v.x = fmaxf(s * x.x, 0.f);
    v.y = fmaxf(s * x.y, 0.f);
    v.z = fmaxf(s * x.z, 0.f);
    v.w = fmaxf(s * x.w, 0.f);
    float pv = wsum(dot4(v, v));
    float vn = fmaxf(sqrtf(pv), EPSF);
    float s2 = tanhf(vn) / vn;
    float4 h;
    h.x = s2 * v.x;
    h.y = s2 * v.y;
    h.z = s2 * v.z;
    h.w = s2 * v.w;
    *reinterpret_cast<float4*>(h1 + (size_t)(b4 + w) * 256 + l4) = h;
  }
#undef LOADA
#undef LOADB
#undef MFMAALL
}

// Kernel 2: 64 blocks x 256 threads (round-9 structure, DPP reductions).
__global__ __launch_bounds__(256) void
k2_out(const float* __restrict__ h1, const float* __restrict__ W2,
       const float* __restrict__ b2, const float* __restrict__ Wl,
       const float* __restrict__ bl, float* __restrict__ out) {
  const int j = blockIdx.x;
  const int tid = threadIdx.x;
  const int w = tid >> 6;
  const int lane = tid & 63;
  const int l4 = lane << 2;

  __shared__ float hrows[16][256];  // 16 KB
  __shared__ float xs[256];
  __shared__ float pp[4][256];      // 4 KB

  const float* base = h1 + (size_t)j * 4096;
#pragma unroll
  for (int t = 0; t < 4; ++t) {
    const int idx = (t << 8) + tid;        // 0..1023 float4 slots
    const int r = idx >> 6;
    const int c4 = (idx & 63) << 2;
    float4 f = *reinterpret_cast<const float4*>(base + r * 256 + c4);
    f.x *= 0.25f; f.y *= 0.25f; f.z *= 0.25f; f.w *= 0.25f;
    *reinterpret_cast<float4*>(&hrows[r][c4]) = f;
  }
  __syncthreads();

  float4 x = make_float4(0.f, 0.f, 0.f, 0.f);
  if (w == 0) {
    x = *reinterpret_cast<const float4*>(&hrows[0][l4]);
#pragma unroll 1
    for (int kk = 1; kk < 16; ++kk) {
      const float4 y = *reinterpret_cast<const float4*>(&hrows[kk][l4]);
      x = mobius_step(x, y);
    }
    *reinterpret_cast<float4*>(&xs[l4]) = x;
  }
  __syncthreads();

  // mobius_matvec(x, W2): wave w accumulates d in [64w, 64w+64).
  {
    float4 p = make_float4(0.f, 0.f, 0.f, 0.f);
    const int dbase = w << 6;
    for (int d = 0; d < 64; ++d) {
      const float xd = xs[dbase + d];
      const float4 wv =
          *reinterpret_cast<const float4*>(W2 + (size_t)(dbase + d) * 256 + l4);
      p.x = fmaf(xd, wv.x, p.x);
      p.y = fmaf(xd, wv.y, p.y);
      p.z = fmaf(xd, wv.z, p.z);
      p.w = fmaf(xd, wv.w, p.w);
    }
    *reinterpret_cast<float4*>(&pp[w][l4]) = p;
  }
  __syncthreads();

  if (w == 0) {
    float4 mx;
    mx.x = pp[0][l4 + 0] + pp[1][l4 + 0] + pp[2][l4 + 0] + pp[3][l4 + 0];
    mx.y = pp[0][l4 + 1] + pp[1][l4 + 1] + pp[2][l4 + 1] + pp[3][l4 + 1];
    mx.z = pp[0][l4 + 2] + pp[1][l4 + 2] + pp[2][l4 + 2] + pp[3][l4 + 2];
    mx.w = pp[0][l4 + 3] + pp[1][l4 + 3] + pp[2][l4 + 3] + pp[3][l4 + 3];
    {
      float px = wsum(dot4(x, x));
      float pm = wsum(dot4(mx, mx));
      float xn = fminf(fmaxf(sqrtf(px), EPSF), MAXNF);
      float mxn = fmaxf(sqrtf(pm), EPSF);
      float s = tanhf(mxn / xn * atanhf(xn)) / mxn;
      s *= 0.25f;  // rst * norm
      x.x = s * mx.x; x.y = s * mx.y; x.z = s * mx.z; x.w = s * mx.w;
    }
    {
      const float4 b = *reinterpret_cast<const float4*>(b2 + l4);
      x = mobius_step(x, b);
    }
    float pn = wsum(dot4(x, x));
    float yn = fminf(fmaxf(sqrtf(pn), EPSF), MAXNF);
    float s = atanhf(yn) / yn;
    float4 v;
    v.x = fmaxf(s * x.x, 0.f);
    v.y = fmaxf(s * x.y, 0.f);
    v.z = fmaxf(s * x.z, 0.f);
    v.w = fmaxf(s * x.w, 0.f);
    float pv = wsum(dot4(v, v));
    float vn = fmaxf(sqrtf(pv), EPSF);
    float s2 = tanhf(vn) / vn;
    float4 h;
    h.x = s2 * v.x; h.y = s2 * v.y; h.z = s2 * v.z; h.w = s2 * v.w;

    *reinterpret_cast<float4*>(&xs[l4]) = h;
    float m = 0.f;
    for (int d = 0; d < 256; d += 4) {
      const float4 wv =
          *reinterpret_cast<const float4*>(Wl + (size_t)lane * 256 + d);
      m = fmaf(wv.x, xs[d + 0], m);
      m = fmaf(wv.y, xs[d + 1], m);
      m = fmaf(wv.z, xs[d + 2], m);
      m = fmaf(wv.w, xs[d + 3], m);
    }
    float ph = wsum(dot4(h, h));
    float pmm = wsum(m * m);
    float hn = fminf(fmaxf(sqrtf(ph), EPSF), MAXNF);
    float mn = fmaxf(sqrtf(pmm), EPSF);
    float sc = tanhf(mn / hn * atanhf(hn)) / mn;
    float mo = sc * m;
    float bo = bl[lane];
    float pxx = wsum(mo * mo);
    float pbb = wsum(bo * bo);
    float pxb = wsum(mo * bo);
    float cx = 1.f + 2.f * pxb + pbb;
    float cy = 1.f - pxx;
    float inv = 1.f / fmaxf(1.f + 2.f * pxb + pxx * pbb, EPSF);
    out[j * 64 + lane] = (cx * mo + cy * bo) * inv;
  }
}

extern "C" void kernel_launch(void* const* d_in, const int* in_sizes, int n_in,
                              void* d_out, int out_size, void* d_ws,
                              size_t ws_size, hipStream_t stream) {
  const float* features = (const float*)d_in[0];
  const float* W1 = (const float*)d_in[1];
  const float* b1 = (const float*)d_in[2];
  const float* W2 = (const float*)d_in[3];
  const float* b2 = (const float*)d_in[4];
  const float* Wl = (const float*)d_in[5];
  const float* bl = (const float*)d_in[6];
  const int* src_idx = (const int*)d_in[7];
  const int* to_fetch = (const int*)d_in[8];
  float* out = (float*)d_out;

  float* h1 = (float*)d_ws;  // 1 MB
  unsigned short* whi = (unsigned short*)((char*)d_ws + (1u << 20));   // 256 KB
  unsigned short* wlo = (unsigned short*)((char*)d_ws + (1u << 20) + (1u << 18));

  k0_pack<<<64, 256, 0, stream>>>(W1, whi, wlo);
  k1_h1<<<256, 512, 0, stream>>>(features, whi, wlo, b1, src_idx, to_fetch, h1);
  k2_out<<<64, 256, 0, stream>>>(h1, W2, b2, Wl, bl, out);
}